// Round 7
// baseline (199.472 us; speedup 1.0000x reference)
//
#include <hip/hip_runtime.h>
#include <hip/hip_bf16.h>
#include <stdint.h>
#include <math.h>

// Problem constants
#define D_MODEL 1024
#define NHEAD   16
#define DHEAD   64
#define BATCH   2
#define SEQ     2048
#define M_TOK   (BATCH * SEQ)   // 4096 tokens

// Q pre-scale: 1/sqrt(DHEAD) * log2(e), folded into the Q projection so the
// QK^T MFMA result is directly the exp2 argument.
#define QSCALE 0.18033688011112042f

typedef __attribute__((ext_vector_type(8))) short   short8;
typedef __attribute__((ext_vector_type(8))) __bf16  bf16x8;
typedef __attribute__((ext_vector_type(4))) float   f32x4;

__device__ inline short f2bf(float f) {           // RNE
  unsigned int u = __builtin_bit_cast(unsigned int, f);
  unsigned int r = (u + 0x7FFFu + ((u >> 16) & 1u)) >> 16;
  return (short)(unsigned short)r;
}
__device__ inline short f2bf_fast(float f) {      // round-nearest (ties away), 2 ops
  unsigned int u = __builtin_bit_cast(unsigned int, f);
  return (short)(unsigned short)((u + 0x8000u) >> 16);
}

// async global -> LDS, 16B per lane. LDS dest must be wave-uniform base + lane*16.
__device__ inline void gl_lds16(const void* g, void* l) {
  __builtin_amdgcn_global_load_lds((__attribute__((address_space(1))) void*)(g),
                                   (__attribute__((address_space(3))) void*)(l),
                                   16, 0, 0);
}

__device__ inline bf16x8 lds_frag(const short* p) {
  return *(const bf16x8*)(p);
}

// ---------------------------------------------------------------------------
// Prep kernel (fused): z=0..3 -> transpose+convert weight matrix z
// (W[k][n] fp32 -> Wt[n][k] bf16); z=4 -> convert x fp32 -> bf16.
// Grid (16,16,5), 256 threads. One launch instead of two.
// ---------------------------------------------------------------------------
__global__ __launch_bounds__(256) void prep(const float* __restrict__ x,
                                            short* __restrict__ xb,
                                            const float* __restrict__ w0,
                                            const float* __restrict__ w1,
                                            const float* __restrict__ w2,
                                            const float* __restrict__ w3,
                                            short* __restrict__ out) {
  const int t = threadIdx.x;
  if (blockIdx.z == 4) {
    // convert x: 256 blocks (by*16+bx), 16384 elems each
    size_t base = ((size_t)blockIdx.y * 16 + blockIdx.x) * 16384;
    const float* in = x + base;
    short* o = xb + base;
#pragma unroll
    for (int i = 0; i < 16; ++i) {
      f32x4 v = *(const f32x4*)(in + (size_t)t * 4 + i * 1024);
      short4 s4;
      s4.x = f2bf(v[0]); s4.y = f2bf(v[1]); s4.z = f2bf(v[2]); s4.w = f2bf(v[3]);
      *(short4*)(o + (size_t)t * 4 + i * 1024) = s4;
    }
    return;
  }
  __shared__ short tile[64][72];
  const float* W = blockIdx.z == 0 ? w0 : blockIdx.z == 1 ? w1 : blockIdx.z == 2 ? w2 : w3;
  short* O = out + (size_t)blockIdx.z * (D_MODEL * (size_t)D_MODEL);
  int n0 = blockIdx.x * 64, k0 = blockIdx.y * 64;
#pragma unroll
  for (int i = 0; i < 16; ++i) {
    int idx = t + 256 * i;
    int r = idx >> 6, c = idx & 63;
    tile[r][c] = f2bf(W[(size_t)(k0 + r) * D_MODEL + n0 + c]);
  }
  __syncthreads();
#pragma unroll
  for (int i = 0; i < 16; ++i) {
    int idx = t + 256 * i;
    int r = idx >> 6, c = idx & 63;
    O[(size_t)(n0 + r) * D_MODEL + k0 + c] = tile[c][r];
  }
}

// ---------------------------------------------------------------------------
// GEMM v2: out[m][n] = A[m][k] * Bt[n][k]^T + bias[n]  (bf16 in, fp32 acc)
// 128xTN tile, 256 threads (4 waves, 64x(TN/2) per wave).
// BK=32 K-steps, TWO token-rows per 128B LDS row (row-pair rp, slot
// ((e<<2)|q)^(rp&7)); full double buffer in the SAME 32KB (no m132 trap);
// gl_lds dest lane-linear, swizzle carried by the per-lane global source;
// frag reads keep the conflict-free floor pattern.
// Loop: sync -> stage(ks+1 -> buf^1) -> compute(ks, buf). ONE barrier/step.
// R6: per-dispatch improved vs v1 (both gemms dropped below the attn 48us
// line; v1 measured 50.2). Kept.
// QKV launch (VT=true): z=0 -> Q scaled by QSCALE; z=2 -> V written transposed
// with MASKED KEY ROWS ZEROED (pm[b][s]==1 -> 0) and the key axis PERMUTED
// within each 32-key block so the attention PV step reads single b128
// fragments (R3: unpermuted cost 4.27M conflict cycles; R4: 74K).
// ---------------------------------------------------------------------------
template <bool OUTF32, bool VT, int TN>
__global__ __launch_bounds__(256) void gemm128(const short* __restrict__ A,
                                               const short* __restrict__ Bt_base,
                                               const float* __restrict__ b0,
                                               const float* __restrict__ b1,
                                               const float* __restrict__ b2,
                                               void* __restrict__ out_base,
                                               short* __restrict__ vt,
                                               const int* __restrict__ pm) {
  constexpr int NI  = TN / 32;        // per-wave n-subtiles (4 or 2)
  constexpr int NBI = (TN * 4) / 256; // B stage slots per thread (2 or 1)
  const int z = blockIdx.z;
  const short* Bt   = Bt_base + (size_t)z * (D_MODEL * (size_t)D_MODEL);
  const float* bias = (z == 0) ? b0 : (z == 1) ? b1 : b2;

  // per-buffer A: [64 row-pairs][8 slots x 8 shorts] = 8KB; B: TN/2 pairs.
  __shared__ short As[2][128 * 32];   // 16 KB total
  __shared__ short Bs[2][TN * 32];    // 16 or 8 KB total

  const int t = threadIdx.x;
  const int lane = t & 63;
  const int wid = t >> 6;
  const int wm = (wid >> 1) * 64, wn = (wid & 1) * (TN / 2);
  const int m0 = blockIdx.x * 128, n0 = blockIdx.y * TN;
  const int cl = lane & 15, q = lane >> 4;

  f32x4 acc[4][NI];
#pragma unroll
  for (int i = 0; i < 4; ++i)
#pragma unroll
    for (int j = 0; j < NI; ++j) acc[i][j] = 0.0f;

  // stage K-step ks (32 cols) into buffer ks&1. Slot d holds global
  // (row = 2*(d>>3) + (x>>2), col = (x&3)*8) with x = (d&7)^((d>>3)&7):
  // dest linear in d (gl_lds requirement), swizzle carried by the source.
  auto stage = [&](int ks) {
    const int bi = ks & 1;
    const int k0 = ks * 32;
#pragma unroll
    for (int i = 0; i < 2; ++i) {       // A: 512 slots
      int d = t + 256 * i;
      int rp = d >> 3, x = (d & 7) ^ (rp & 7);
      gl_lds16(A + (size_t)(m0 + rp * 2 + (x >> 2)) * D_MODEL + k0 + (x & 3) * 8,
               (void*)(As[bi] + d * 8));
    }
#pragma unroll
    for (int i = 0; i < NBI; ++i) {     // B: TN*4 slots
      int d = t + 256 * i;
      int rp = d >> 3, x = (d & 7) ^ (rp & 7);
      gl_lds16(Bt + (size_t)(n0 + rp * 2 + (x >> 2)) * D_MODEL + k0 + (x & 3) * 8,
               (void*)(Bs[bi] + d * 8));
    }
  };

  stage(0);
  for (int ks = 0; ks < 32; ++ks) {
    __syncthreads();                 // drains buf[ks&1] loads (issued last step)
    if (ks + 1 < 32) stage(ks + 1);  // prefetch into the other buffer
    const short* Ap = As[ks & 1];
    const short* Bp = Bs[ks & 1];

    bf16x8 af[4], bfr[NI];
#pragma unroll
    for (int mi = 0; mi < 4; ++mi) {
      int row = wm + mi * 16 + cl;
      int rp = row >> 1;
      int pos = (((row & 1) << 2) | q) ^ (rp & 7);
      af[mi] = lds_frag(Ap + rp * 64 + pos * 8);
    }
#pragma unroll
    for (int ni = 0; ni < NI; ++ni) {
      int row = wn + ni * 16 + cl;
      int rp = row >> 1;
      int pos = (((row & 1) << 2) | q) ^ (rp & 7);
      bfr[ni] = lds_frag(Bp + rp * 64 + pos * 8);
    }
#pragma unroll
    for (int mi = 0; mi < 4; ++mi)
#pragma unroll
      for (int ni = 0; ni < NI; ++ni)
        acc[mi][ni] = __builtin_amdgcn_mfma_f32_16x16x32_bf16(af[mi], bfr[ni], acc[mi][ni], 0, 0, 0);
  }

  // Epilogue: C/D layout col=lane&15, row=(lane>>4)*4+reg
  const float oscale = (VT && z == 0) ? QSCALE : 1.0f;
  int4 mm[4];
  if (VT && z == 2) {
#pragma unroll
    for (int mi = 0; mi < 4; ++mi) {
      int rbase = m0 + wm + mi * 16 + q * 4;
      mm[mi] = *(const int4*)(pm + (size_t)(rbase >> 11) * SEQ + (rbase & (SEQ - 1)));
    }
  }
#pragma unroll
  for (int ni = 0; ni < NI; ++ni) {
    int col = n0 + wn + ni * 16 + cl;
    float bv = bias[col];
#pragma unroll
    for (int mi = 0; mi < 4; ++mi) {
      int rbase = m0 + wm + mi * 16 + q * 4;
      if (VT && z == 2) {
        short4 o4;
        o4.x = (mm[mi].x == 1) ? (short)0 : f2bf_fast(acc[mi][ni][0] + bv);
        o4.y = (mm[mi].y == 1) ? (short)0 : f2bf_fast(acc[mi][ni][1] + bv);
        o4.z = (mm[mi].z == 1) ? (short)0 : f2bf_fast(acc[mi][ni][2] + bv);
        o4.w = (mm[mi].w == 1) ? (short)0 : f2bf_fast(acc[mi][ni][3] + bv);
        int btok = rbase >> 11;           // token block -> batch
        int s    = rbase & (SEQ - 1);
        // key-axis permutation within each 32-key block: storage p holds key
        // with bits rearranged (p[4:3]=key[3:2], p[2]=key[4], p[1:0]=key[1:0])
        // -> attn PV reads become contiguous b128 fragments. s is 4-aligned so
        // the short4 store stays contiguous.
        int sp = (s & ~31) | ((s & 16) >> 2) | ((s & 12) << 1) | (s & 3);
        *(short4*)(vt + (size_t)btok * ((size_t)D_MODEL * SEQ) + (size_t)col * SEQ + sp) = o4;
      } else {
#pragma unroll
        for (int r = 0; r < 4; ++r) {
          float v = (acc[mi][ni][r] + bv) * oscale;
          size_t idx = (size_t)(rbase + r) * D_MODEL + col;
          if (OUTF32) {
            ((float*)out_base)[idx] = v;
          } else {
            short* out = (short*)out_base + (size_t)z * ((size_t)M_TOK * D_MODEL);
            out[idx] = f2bf_fast(v);
          }
        }
      }
    }
  }
}

// ---------------------------------------------------------------------------
// Flash attention v10: 64 q-rows per wave (K-fragment amortization).
// R6 ledger @48us (115K cy/CU): LDS reads 49K cy (43%, top pipe) because all
// 8 waves re-pull the same 16KB K/V half-tile per compute; VALU 34% (exp2
// floor 33K cy, irreducible); MFMA 27%. LDS-read volume = waves/block x
// bytes/wave, and K-frags amortize over a wave's q-rows -> v10 gives each
// wave 64 q-rows (256-thread / 4-wave blocks, wave = (rg, kvh)): same 16KB
// read now feeds 64 MFMA -> per-CU LDS reads halve (49K -> 24.6K cy).
// Cost: VGPR ~215 -> 2 waves/SIMD (vs 4), compensated by 2x per-wave ILP
// (32 independent MFMA per phase) + the dbuf DMA pipeline.
// Keeps: in-register P, permuted-V b128 frags, additive-mask C-init,
// ping-pong gl_lds staging with one barrier per phase.
// ---------------------------------------------------------------------------
__global__ __launch_bounds__(256) void attn_flash(const short* __restrict__ Q,
                                                  const short* __restrict__ K,
                                                  const short* __restrict__ Vt,
                                                  const int*   __restrict__ mask,
                                                  short* __restrict__ ctx) {
  const int qb = blockIdx.x;   // 0..15
  const int h  = blockIdx.y;   // 0..15
  const int b  = blockIdx.z;   // 0..1

  // shorts: bufA[16384] | bufB[16384] | Usf f32[2048] (additive bias)
  // bufX = K[2 halves][64key][64d] ++ Vt[2 halves][64d][64key], swizzled.
  // prologue: Q tile staged into bufB[0:8192]. epilogue: redO f32[128][64]
  // over bufA (32KB), redL f32[128][4] over bufB start.
  __shared__ __align__(16) short smem[36864];
  short* bufA = smem;
  short* bufB = smem + 16384;
  float* Usf  = (float*)(smem + 32768);

  const int t = threadIdx.x;
  const int lane = t & 63;
  const int wid = t >> 6;           // 0..3
  const int rg  = wid >> 1;         // row-group 0..1 (64 q-rows each)
  const int kvh = wid & 1;          // kv half: keys [kvh*1024, kvh*1024+1024)
  const int cl = lane & 15, q = lane >> 4;
  const int sw = cl & 7;

  const size_t rowQ0 = (size_t)b * SEQ + (size_t)qb * 128;
  const size_t rowK0 = (size_t)b * SEQ;
  const size_t vbase = ((size_t)b * D_MODEL + h * DHEAD) * SEQ;

  // staging: 8 chunks/thread per 128-key tile (4 regions x 2 sub-passes).
  // chunk c = t (+256): row = c>>3, cp = c&7; c+256 -> row+32, same swizzle
  // (row&7 invariant) so the second pass is base + 32 rows.
  const int srow = t >> 3, scp = t & 7;
  const int scol = (scp ^ (srow & 7)) * 8;
  const short* Kg0 = K + (rowK0 + srow) * D_MODEL + h * DHEAD + scol;
  const short* Kg1 = K + (rowK0 + 1024 + srow) * D_MODEL + h * DHEAD + scol;
  const short* Vg0 = Vt + vbase + (size_t)srow * SEQ + scol;
  const short* Vg1 = Vt + vbase + (size_t)srow * SEQ + 1024 + scol;

  // DMA-stage one 128-key tile (K both halves + V both halves) into buf.
  auto stage = [&](short* buf, int sn) {
    const short* k0p = Kg0 + (size_t)sn * D_MODEL;
    const short* k1p = Kg1 + (size_t)sn * D_MODEL;
    gl_lds16(k0p,                    (void*)(buf + t * 8));
    gl_lds16(k0p + 32 * D_MODEL,     (void*)(buf + 2048 + t * 8));
    gl_lds16(k1p,                    (void*)(buf + 4096 + t * 8));
    gl_lds16(k1p + 32 * D_MODEL,     (void*)(buf + 6144 + t * 8));
    gl_lds16(Vg0 + sn,               (void*)(buf + 8192 + t * 8));
    gl_lds16(Vg0 + sn + 32 * SEQ,    (void*)(buf + 10240 + t * 8));
    gl_lds16(Vg1 + sn,               (void*)(buf + 12288 + t * 8));
    gl_lds16(Vg1 + sn + 32 * SEQ,    (void*)(buf + 14336 + t * 8));
  };

  // prologue: KV tile 0 -> bufA; Q tile -> bufB[0:8192]; mask bias -> Usf
  stage(bufA, 0);
#pragma unroll
  for (int i = 0; i < 4; ++i) {
    int c = t + 256 * i;
    int row = c >> 3, cp = c & 7;
    gl_lds16(Q + (rowQ0 + row) * D_MODEL + h * DHEAD + ((cp ^ (row & 7)) * 8),
             (void*)(bufB + c * 8));
  }
#pragma unroll
  for (int i = 0; i < 2; ++i) {
    int4 mv = *(const int4*)(mask + (size_t)b * SEQ + t * 8 + i * 4);
    f32x4 u4;
    u4[0] = (mv.x == 1) ? -1e30f : 0.0f;
    u4[1] = (mv.y == 1) ? -1e30f : 0.0f;
    u4[2] = (mv.z == 1) ? -1e30f : 0.0f;
    u4[3] = (mv.w == 1) ? -1e30f : 0.0f;
    *(f32x4*)(Usf + t * 8 + i * 4) = u4;
  }
  __syncthreads();

  // Register-resident Q fragments: wave owns rows [64*rg, 64*rg+64)
  bf16x8 qf[4][2];
#pragma unroll
  for (int rb = 0; rb < 4; ++rb) {
    int row = rg * 64 + rb * 16 + cl;
    qf[rb][0] = lds_frag(bufB + row * 64 + (q ^ sw) * 8);
    qf[rb][1] = lds_frag(bufB + row * 64 + ((4 + q) ^ sw) * 8);
  }

  f32x4 lacc[4], oacc[4][4];
#pragma unroll
  for (int rb = 0; rb < 4; ++rb) {
    lacc[rb] = 0.0f;
#pragma unroll
    for (int dj = 0; dj < 4; ++dj) oacc[rb][dj] = 0.0f;
  }

  // one 64-key compute for this wave's half
  auto compute = [&](const short* buf, int s0) {
    const short* Kp = buf + kvh * 4096;
    const short* Vp = buf + 8192 + kvh * 4096;
    const float* Bp = Usf + kvh * 1024 + s0 + 4 * q;

    // S^T = K Q^T + bias (C-init): C row = key 4q+r (tile j), col = q-row cl
    f32x4 s[4][4];
#pragma unroll
    for (int j = 0; j < 4; ++j) {
      bf16x8 kf0 = lds_frag(Kp + (j * 16 + cl) * 64 + (q ^ sw) * 8);
      bf16x8 kf1 = lds_frag(Kp + (j * 16 + cl) * 64 + ((4 + q) ^ sw) * 8);
      f32x4 cv = *(const f32x4*)(Bp + j * 16);   // broadcast across cl
#pragma unroll
      for (int rb = 0; rb < 4; ++rb) {
        f32x4 sa = cv;
        sa = __builtin_amdgcn_mfma_f32_16x16x32_bf16(kf0, qf[rb][0], sa, 0, 0, 0);
        sa = __builtin_amdgcn_mfma_f32_16x16x32_bf16(kf1, qf[rb][1], sa, 0, 0, 0);
        s[rb][j] = sa;
      }
    }

    // p = exp2(s + bias) in registers (masked -> exact 0); l accumulates f32x4
#pragma unroll
    for (int rb = 0; rb < 4; ++rb)
#pragma unroll
      for (int j = 0; j < 4; ++j) {
#pragma unroll
        for (int r = 0; r < 4; ++r)
          s[rb][j][r] = __builtin_amdgcn_exp2f(s[rb][j][r]);
        lacc[rb] += s[rb][j];
      }

    // pack P to bf16 lane-locally: pf[c] = keys {32c+4q+r} ++ {32c+16+4q+r}
    bf16x8 pf[4][2];
#pragma unroll
    for (int rb = 0; rb < 4; ++rb)
#pragma unroll
      for (int c = 0; c < 2; ++c) {
        bf16x8 v;
        v[0] = (__bf16)s[rb][2 * c][0];
        v[1] = (__bf16)s[rb][2 * c][1];
        v[2] = (__bf16)s[rb][2 * c][2];
        v[3] = (__bf16)s[rb][2 * c][3];
        v[4] = (__bf16)s[rb][2 * c + 1][0];
        v[5] = (__bf16)s[rb][2 * c + 1][1];
        v[6] = (__bf16)s[rb][2 * c + 1][2];
        v[7] = (__bf16)s[rb][2 * c + 1][3];
        pf[rb][c] = v;
      }

    // O^T += V^T P^T. Permuted-V storage: lane (cl,q) frag c's 8 k-slot
    // elements are contiguous at chunk 4c+q -> single b128 (floor pattern).
#pragma unroll
    for (int dj = 0; dj < 4; ++dj) {
      const short* vrow = Vp + (dj * 16 + cl) * 64;
#pragma unroll
      for (int c = 0; c < 2; ++c) {
        bf16x8 vfc = lds_frag(vrow + (((4 * c + q) ^ sw) * 8));
#pragma unroll
        for (int rb = 0; rb < 4; ++rb)
          oacc[rb][dj] = __builtin_amdgcn_mfma_f32_16x16x32_bf16(vfc, pf[rb][c], oacc[rb][dj], 0, 0, 0);
      }
    }
  };

  // main loop: 8 iters x 2 ping-pong phases = 16 tiles of 128 keys.
  // Each phase: ONE barrier, then DMA-stage the next tile into the other
  // buffer (lands during this phase's compute), then compute.
  for (int it = 0; it < 8; ++it) {
    int s0 = it * 128;                 // half-space key offset
    __syncthreads();                   // drains bufA loads (issued last phase)
    stage(bufB, s0 + 64);              // overwrites Q region on it=0 (qf in regs)
    compute(bufA, s0);
    __syncthreads();                   // drains bufB loads
    if (it < 7) stage(bufA, s0 + 128);
    compute(bufB, s0 + 64);
  }

  // ---- combine kv-halves through LDS (O,l are linear in the key axis) ----
  __syncthreads();                       // all compute reads of LDS done
  float hl[4];
#pragma unroll
  for (int rb = 0; rb < 4; ++rb)
    hl[rb] = lacc[rb][0] + lacc[rb][1] + lacc[rb][2] + lacc[rb][3];

  float* redO = (float*)smem;            // 32 KB: 128 slots x 16 f32x4
  float* redL = (float*)(smem + 16384);  // 2 KB: 128 slots x 4 f32
  const int slot = rg * 64 + lane;       // 0..127
  if (kvh) {
#pragma unroll
    for (int rb = 0; rb < 4; ++rb) {
#pragma unroll
      for (int dj = 0; dj < 4; ++dj) {
        int qi = (rb * 4 + dj) ^ (lane & 15);   // XOR-swizzle: spread banks
        *(f32x4*)(redO + slot * 64 + qi * 4) = oacc[rb][dj];
      }
      redL[slot * 4 + rb] = hl[rb];
    }
  }
  __syncthreads();
  if (kvh) return;
#pragma unroll
  for (int rb = 0; rb < 4; ++rb) {
    hl[rb] += redL[slot * 4 + rb];
#pragma unroll
    for (int dj = 0; dj < 4; ++dj) {
      int qi = (rb * 4 + dj) ^ (lane & 15);
      oacc[rb][dj] += *(const f32x4*)(redO + slot * 64 + qi * 4);
    }
  }
  // l: sum over the 4 q-lane groups (lanes ^16, ^32 share the same cl)
#pragma unroll
  for (int rb = 0; rb < 4; ++rb) {
    hl[rb] += __shfl_xor(hl[rb], 16);
    hl[rb] += __shfl_xor(hl[rb], 32);
  }

  // finalize: O^T layout -> lane (cl,q) reg r holds O[row=rg*64+rb*16+cl]
  // [d = dj*16 + 4q + r]; 4 consecutive d per reg -> short4 stores.
#pragma unroll
  for (int rb = 0; rb < 4; ++rb) {
    float inv = (hl[rb] > 0.0f) ? 1.0f / hl[rb] : 0.0f;
    size_t row = rowQ0 + rg * 64 + rb * 16 + cl;
#pragma unroll
    for (int dj = 0; dj < 4; ++dj) {
      short4 o4;
      o4.x = f2bf(oacc[rb][dj][0] * inv);
      o4.y = f2bf(oacc[rb][dj][1] * inv);
      o4.z = f2bf(oacc[rb][dj][2] * inv);
      o4.w = f2bf(oacc[rb][dj][3] * inv);
      *(short4*)(ctx + row * D_MODEL + h * DHEAD + dj * 16 + q * 4) = o4;
    }
  }
}

// ---------------------------------------------------------------------------
extern "C" void kernel_launch(void* const* d_in, const int* in_sizes, int n_in,
                              void* d_out, int out_size, void* d_ws, size_t ws_size,
                              hipStream_t stream) {
  (void)in_sizes; (void)n_in; (void)out_size; (void)ws_size;

  const float* x  = (const float*)d_in[0];
  const int*   pm = (const int*)  d_in[1];
  const float* Wq = (const float*)d_in[2];
  const float* bq = (const float*)d_in[3];
  const float* Wk = (const float*)d_in[4];
  const float* bk = (const float*)d_in[5];
  const float* Wv = (const float*)d_in[6];
  const float* bv = (const float*)d_in[7];
  const float* Wo = (const float*)d_in[8];
  const float* bo = (const float*)d_in[9];

  const size_t WMAT = (size_t)D_MODEL * D_MODEL;   // 1M elems
  const size_t TOKD = (size_t)M_TOK * D_MODEL;     // 4M elems

  short* base = (short*)d_ws;
  short* Wt = base;              // 4 transposed bf16 weights: 8 MB
  short* xb = base + 4 * WMAT;   // bf16 x: 8 MB
  short* Qw = xb + TOKD;         // 8 MB (z=0, pre-scaled by QSCALE)
  short* Kw = Qw + TOKD;         // 8 MB (z=1)
  short* Vtw = Kw + TOKD;        // 8 MB Vt[b][n][s], masked rows zeroed, key-permuted
  short* Cw = Vtw + TOKD;        // 8 MB  (total 48 MB of ws)

  prep<<<dim3(16, 16, 5), 256, 0, stream>>>(x, xb, Wq, Wk, Wv, Wo, Wt);
  gemm128<false, true, 128><<<dim3(M_TOK / 128, D_MODEL / 128, 3), 256, 0, stream>>>(
      xb, Wt, bq, bk, bv, Qw, Vtw, pm);
  attn_flash<<<dim3(SEQ / 128, NHEAD, BATCH), 256, 0, stream>>>(Qw, Kw, Vtw, pm, Cw);
  gemm128<true, false, 64><<<dim3(M_TOK / 128, D_MODEL / 64, 1), 256, 0, stream>>>(
      Cw, Wt + 3 * WMAT, bo, bo, bo, d_out, nullptr, nullptr);
}

// Round 8
// 196.046 us; speedup vs baseline: 1.0175x; 1.0175x over previous
//
#include <hip/hip_runtime.h>
#include <hip/hip_bf16.h>
#include <stdint.h>
#include <math.h>

// Problem constants
#define D_MODEL 1024
#define NHEAD   16
#define DHEAD   64
#define BATCH   2
#define SEQ     2048
#define M_TOK   (BATCH * SEQ)   // 4096 tokens

// Q pre-scale: 1/sqrt(DHEAD) * log2(e), folded into the Q projection so the
// QK^T MFMA result is directly the exp2 argument.
#define QSCALE 0.18033688011112042f

typedef __attribute__((ext_vector_type(8))) short   short8;
typedef __attribute__((ext_vector_type(8))) __bf16  bf16x8;
typedef __attribute__((ext_vector_type(4))) float   f32x4;

__device__ inline short f2bf(float f) {           // RNE
  unsigned int u = __builtin_bit_cast(unsigned int, f);
  unsigned int r = (u + 0x7FFFu + ((u >> 16) & 1u)) >> 16;
  return (short)(unsigned short)r;
}
__device__ inline short f2bf_fast(float f) {      // round-nearest (ties away), 2 ops
  unsigned int u = __builtin_bit_cast(unsigned int, f);
  return (short)(unsigned short)((u + 0x8000u) >> 16);
}

// async global -> LDS, 16B per lane. LDS dest must be wave-uniform base + lane*16.
__device__ inline void gl_lds16(const void* g, void* l) {
  __builtin_amdgcn_global_load_lds((__attribute__((address_space(1))) void*)(g),
                                   (__attribute__((address_space(3))) void*)(l),
                                   16, 0, 0);
}

__device__ inline bf16x8 lds_frag(const short* p) {
  return *(const bf16x8*)(p);
}

// ---------------------------------------------------------------------------
// Prep kernel (fused): z=0..3 -> transpose+convert weight matrix z
// (W[k][n] fp32 -> Wt[n][k] bf16); z=4 -> convert x fp32 -> bf16.
// Grid (16,16,5), 256 threads. One launch instead of two.
// ---------------------------------------------------------------------------
__global__ __launch_bounds__(256) void prep(const float* __restrict__ x,
                                            short* __restrict__ xb,
                                            const float* __restrict__ w0,
                                            const float* __restrict__ w1,
                                            const float* __restrict__ w2,
                                            const float* __restrict__ w3,
                                            short* __restrict__ out) {
  const int t = threadIdx.x;
  if (blockIdx.z == 4) {
    // convert x: 256 blocks (by*16+bx), 16384 elems each
    size_t base = ((size_t)blockIdx.y * 16 + blockIdx.x) * 16384;
    const float* in = x + base;
    short* o = xb + base;
#pragma unroll
    for (int i = 0; i < 16; ++i) {
      f32x4 v = *(const f32x4*)(in + (size_t)t * 4 + i * 1024);
      short4 s4;
      s4.x = f2bf(v[0]); s4.y = f2bf(v[1]); s4.z = f2bf(v[2]); s4.w = f2bf(v[3]);
      *(short4*)(o + (size_t)t * 4 + i * 1024) = s4;
    }
    return;
  }
  __shared__ short tile[64][72];
  const float* W = blockIdx.z == 0 ? w0 : blockIdx.z == 1 ? w1 : blockIdx.z == 2 ? w2 : w3;
  short* O = out + (size_t)blockIdx.z * (D_MODEL * (size_t)D_MODEL);
  int n0 = blockIdx.x * 64, k0 = blockIdx.y * 64;
#pragma unroll
  for (int i = 0; i < 16; ++i) {
    int idx = t + 256 * i;
    int r = idx >> 6, c = idx & 63;
    tile[r][c] = f2bf(W[(size_t)(k0 + r) * D_MODEL + n0 + c]);
  }
  __syncthreads();
#pragma unroll
  for (int i = 0; i < 16; ++i) {
    int idx = t + 256 * i;
    int r = idx >> 6, c = idx & 63;
    O[(size_t)(n0 + r) * D_MODEL + k0 + c] = tile[c][r];
  }
}

// ---------------------------------------------------------------------------
// GEMM v2: out[m][n] = A[m][k] * Bt[n][k]^T + bias[n]  (bf16 in, fp32 acc)
// 128xTN tile, 256 threads (4 waves, 64x(TN/2) per wave).
// BK=32 K-steps, TWO token-rows per 128B LDS row (row-pair rp, slot
// ((e<<2)|q)^(rp&7)); full double buffer in the SAME 32KB (no m132 trap);
// gl_lds dest lane-linear, swizzle carried by the per-lane global source;
// frag reads keep the conflict-free floor pattern.
// Loop: sync -> stage(ks+1 -> buf^1) -> compute(ks, buf). ONE barrier/step.
// R6/R7 per-dispatch: both gemms < 48us (v1 QKV was 50.2). Kept.
// QKV launch (VT=true): z=0 -> Q scaled by QSCALE; z=2 -> V written transposed
// with MASKED KEY ROWS ZEROED (pm[b][s]==1 -> 0) and the key axis PERMUTED
// within each 32-key block so the attention PV step reads single b128
// fragments (R3: unpermuted cost 4.27M conflict cycles; R4: 74K).
// ---------------------------------------------------------------------------
template <bool OUTF32, bool VT, int TN>
__global__ __launch_bounds__(256) void gemm128(const short* __restrict__ A,
                                               const short* __restrict__ Bt_base,
                                               const float* __restrict__ b0,
                                               const float* __restrict__ b1,
                                               const float* __restrict__ b2,
                                               void* __restrict__ out_base,
                                               short* __restrict__ vt,
                                               const int* __restrict__ pm) {
  constexpr int NI  = TN / 32;        // per-wave n-subtiles (4 or 2)
  constexpr int NBI = (TN * 4) / 256; // B stage slots per thread (2 or 1)
  const int z = blockIdx.z;
  const short* Bt   = Bt_base + (size_t)z * (D_MODEL * (size_t)D_MODEL);
  const float* bias = (z == 0) ? b0 : (z == 1) ? b1 : b2;

  // per-buffer A: [64 row-pairs][8 slots x 8 shorts] = 8KB; B: TN/2 pairs.
  __shared__ short As[2][128 * 32];   // 16 KB total
  __shared__ short Bs[2][TN * 32];    // 16 or 8 KB total

  const int t = threadIdx.x;
  const int lane = t & 63;
  const int wid = t >> 6;
  const int wm = (wid >> 1) * 64, wn = (wid & 1) * (TN / 2);
  const int m0 = blockIdx.x * 128, n0 = blockIdx.y * TN;
  const int cl = lane & 15, q = lane >> 4;

  f32x4 acc[4][NI];
#pragma unroll
  for (int i = 0; i < 4; ++i)
#pragma unroll
    for (int j = 0; j < NI; ++j) acc[i][j] = 0.0f;

  // stage K-step ks (32 cols) into buffer ks&1. Slot d holds global
  // (row = 2*(d>>3) + (x>>2), col = (x&3)*8) with x = (d&7)^((d>>3)&7):
  // dest linear in d (gl_lds requirement), swizzle carried by the source.
  auto stage = [&](int ks) {
    const int bi = ks & 1;
    const int k0 = ks * 32;
#pragma unroll
    for (int i = 0; i < 2; ++i) {       // A: 512 slots
      int d = t + 256 * i;
      int rp = d >> 3, x = (d & 7) ^ (rp & 7);
      gl_lds16(A + (size_t)(m0 + rp * 2 + (x >> 2)) * D_MODEL + k0 + (x & 3) * 8,
               (void*)(As[bi] + d * 8));
    }
#pragma unroll
    for (int i = 0; i < NBI; ++i) {     // B: TN*4 slots
      int d = t + 256 * i;
      int rp = d >> 3, x = (d & 7) ^ (rp & 7);
      gl_lds16(Bt + (size_t)(n0 + rp * 2 + (x >> 2)) * D_MODEL + k0 + (x & 3) * 8,
               (void*)(Bs[bi] + d * 8));
    }
  };

  stage(0);
  for (int ks = 0; ks < 32; ++ks) {
    __syncthreads();                 // drains buf[ks&1] loads (issued last step)
    if (ks + 1 < 32) stage(ks + 1);  // prefetch into the other buffer
    const short* Ap = As[ks & 1];
    const short* Bp = Bs[ks & 1];

    bf16x8 af[4], bfr[NI];
#pragma unroll
    for (int mi = 0; mi < 4; ++mi) {
      int row = wm + mi * 16 + cl;
      int rp = row >> 1;
      int pos = (((row & 1) << 2) | q) ^ (rp & 7);
      af[mi] = lds_frag(Ap + rp * 64 + pos * 8);
    }
#pragma unroll
    for (int ni = 0; ni < NI; ++ni) {
      int row = wn + ni * 16 + cl;
      int rp = row >> 1;
      int pos = (((row & 1) << 2) | q) ^ (rp & 7);
      bfr[ni] = lds_frag(Bp + rp * 64 + pos * 8);
    }
#pragma unroll
    for (int mi = 0; mi < 4; ++mi)
#pragma unroll
      for (int ni = 0; ni < NI; ++ni)
        acc[mi][ni] = __builtin_amdgcn_mfma_f32_16x16x32_bf16(af[mi], bfr[ni], acc[mi][ni], 0, 0, 0);
  }

  // Epilogue: C/D layout col=lane&15, row=(lane>>4)*4+reg
  const float oscale = (VT && z == 0) ? QSCALE : 1.0f;
  int4 mm[4];
  if (VT && z == 2) {
#pragma unroll
    for (int mi = 0; mi < 4; ++mi) {
      int rbase = m0 + wm + mi * 16 + q * 4;
      mm[mi] = *(const int4*)(pm + (size_t)(rbase >> 11) * SEQ + (rbase & (SEQ - 1)));
    }
  }
#pragma unroll
  for (int ni = 0; ni < NI; ++ni) {
    int col = n0 + wn + ni * 16 + cl;
    float bv = bias[col];
#pragma unroll
    for (int mi = 0; mi < 4; ++mi) {
      int rbase = m0 + wm + mi * 16 + q * 4;
      if (VT && z == 2) {
        short4 o4;
        o4.x = (mm[mi].x == 1) ? (short)0 : f2bf_fast(acc[mi][ni][0] + bv);
        o4.y = (mm[mi].y == 1) ? (short)0 : f2bf_fast(acc[mi][ni][1] + bv);
        o4.z = (mm[mi].z == 1) ? (short)0 : f2bf_fast(acc[mi][ni][2] + bv);
        o4.w = (mm[mi].w == 1) ? (short)0 : f2bf_fast(acc[mi][ni][3] + bv);
        int btok = rbase >> 11;           // token block -> batch
        int s    = rbase & (SEQ - 1);
        // key-axis permutation within each 32-key block: storage p holds key
        // with bits rearranged (p[4:3]=key[3:2], p[2]=key[4], p[1:0]=key[1:0])
        // -> attn PV reads become contiguous b128 fragments. s is 4-aligned so
        // the short4 store stays contiguous.
        int sp = (s & ~31) | ((s & 16) >> 2) | ((s & 12) << 1) | (s & 3);
        *(short4*)(vt + (size_t)btok * ((size_t)D_MODEL * SEQ) + (size_t)col * SEQ + sp) = o4;
      } else {
#pragma unroll
        for (int r = 0; r < 4; ++r) {
          float v = (acc[mi][ni][r] + bv) * oscale;
          size_t idx = (size_t)(rbase + r) * D_MODEL + col;
          if (OUTF32) {
            ((float*)out_base)[idx] = v;
          } else {
            short* out = (short*)out_base + (size_t)z * ((size_t)M_TOK * D_MODEL);
            out[idx] = f2bf_fast(v);
          }
        }
      }
    }
  }
}

// ---------------------------------------------------------------------------
// Flash attention v11 = v9 (proven 48.0us) + T5 s_setprio around MFMA
// clusters. R7's v10 (64q/wave) REGRESSED 48->73us: 184 VGPR crossed the
// 128-VGPR occupancy cliff (2 waves/SIMD), MfmaUtil 27.5->17.6 -- the
// latency-hiding loss beat the 2x LDS-read saving. 64q/wave at <=128 VGPR
// is infeasible (oacc 64 + qf 32 alone = 96). Reverted.
// setprio: v9's 8 waves sit in diverse phases (2 kv-half roles x staggered
// staging) -- the regime where setprio was A/B-verified on attn (+4-7%,
// m191); null only on lockstep GEMM (m190), so gemms untouched.
// Keeps: in-register P, permuted-V b128 frags, additive-mask C-init,
// ping-pong gl_lds staging with one barrier per phase, in-block KV-split.
// ---------------------------------------------------------------------------
__global__ __launch_bounds__(512) void attn_flash(const short* __restrict__ Q,
                                                  const short* __restrict__ K,
                                                  const short* __restrict__ Vt,
                                                  const int*   __restrict__ mask,
                                                  short* __restrict__ ctx) {
  const int qb = blockIdx.x;   // 0..15
  const int h  = blockIdx.y;   // 0..15
  const int b  = blockIdx.z;   // 0..1

  // shorts: bufA[16384] | bufB[16384] | Usf f32[2048] (additive bias)
  // bufX = K[2 halves][64key][64d] ++ Vt[2 halves][64d][64key], swizzled.
  // prologue: Q tile staged into bufB[0:8192]. epilogue: redO over bufA,
  // redL over bufB start.
  __shared__ __align__(16) short smem[36864];
  short* bufA = smem;
  short* bufB = smem + 16384;
  float* Usf  = (float*)(smem + 32768);

  const int t = threadIdx.x;
  const int lane = t & 63;
  const int wid = t >> 6;           // 0..7
  const int wg  = wid >> 1;         // row-group 0..3 (32 q-rows each)
  const int kvh = wid & 1;          // kv half: keys [kvh*1024, kvh*1024+1024)
  const int cl = lane & 15, q = lane >> 4;
  const int sw = cl & 7;

  const size_t rowQ0 = (size_t)b * SEQ + (size_t)qb * 128;
  const size_t rowK0 = (size_t)b * SEQ;
  const size_t vbase = ((size_t)b * D_MODEL + h * DHEAD) * SEQ;

  // per-thread staging addresses (thread t owns LDS chunk t*16B; global
  // source pre-swizzled so LDS reads can XOR-deswizzle)
  const int srow = t >> 3, scp = t & 7;
  const int scol = (scp ^ (srow & 7)) * 8;
  const short* Kg0 = K + (rowK0 + srow) * D_MODEL + h * DHEAD + scol;
  const short* Kg1 = K + (rowK0 + 1024 + srow) * D_MODEL + h * DHEAD + scol;
  const short* Vg0 = Vt + vbase + (size_t)srow * SEQ + scol;
  const short* Vg1 = Vt + vbase + (size_t)srow * SEQ + 1024 + scol;

  // DMA-stage one 128-key tile (64/half K + V) into buf. 4 chunks/thread.
  auto stage = [&](short* buf, int sn) {
    gl_lds16(Kg0 + (size_t)sn * D_MODEL, (void*)(buf + t * 8));
    gl_lds16(Kg1 + (size_t)sn * D_MODEL, (void*)(buf + 4096 + t * 8));
    gl_lds16(Vg0 + sn,                   (void*)(buf + 8192 + t * 8));
    gl_lds16(Vg1 + sn,                   (void*)(buf + 8192 + 4096 + t * 8));
  };

  // prologue: KV tile 0 -> bufA; Q tile -> bufB[0:8192]; mask bias -> Usf
  stage(bufA, 0);
#pragma unroll
  for (int i = 0; i < 2; ++i) {
    int c = t + 512 * i;
    int row = c >> 3, cp = c & 7;
    gl_lds16(Q + (rowQ0 + row) * D_MODEL + h * DHEAD + ((cp ^ (row & 7)) * 8),
             (void*)(bufB + c * 8));
  }
  {
    int4 mv = *(const int4*)(mask + (size_t)b * SEQ + t * 4);
    f32x4 u4;
    u4[0] = (mv.x == 1) ? -1e30f : 0.0f;
    u4[1] = (mv.y == 1) ? -1e30f : 0.0f;
    u4[2] = (mv.z == 1) ? -1e30f : 0.0f;
    u4[3] = (mv.w == 1) ? -1e30f : 0.0f;
    *(f32x4*)(Usf + t * 4) = u4;
  }
  __syncthreads();

  // Register-resident Q fragments: wave owns rows [32*wg, 32*wg+32)
  bf16x8 qf[2][2];
#pragma unroll
  for (int rb = 0; rb < 2; ++rb) {
    int row = wg * 32 + rb * 16 + cl;
    qf[rb][0] = lds_frag(bufB + row * 64 + (q ^ sw) * 8);
    qf[rb][1] = lds_frag(bufB + row * 64 + ((4 + q) ^ sw) * 8);
  }

  f32x4 lacc[2], oacc[2][4];
#pragma unroll
  for (int rb = 0; rb < 2; ++rb) {
    lacc[rb] = 0.0f;
#pragma unroll
    for (int dj = 0; dj < 4; ++dj) oacc[rb][dj] = 0.0f;
  }

  // one 128-key tile (64 keys from this wave's half)
  auto compute = [&](const short* buf, int s0) {
    const short* Kp = buf + kvh * 4096;
    const short* Vp = buf + 8192 + kvh * 4096;
    const float* Bp = Usf + kvh * 1024 + s0 + 4 * q;

    // S^T = K Q^T + bias (C-init): C row = key 4g+r (tile j), col = q-row cl
    f32x4 s[2][4];
    __builtin_amdgcn_s_setprio(1);
#pragma unroll
    for (int j = 0; j < 4; ++j) {
      bf16x8 kf0 = lds_frag(Kp + (j * 16 + cl) * 64 + (q ^ sw) * 8);
      bf16x8 kf1 = lds_frag(Kp + (j * 16 + cl) * 64 + ((4 + q) ^ sw) * 8);
      f32x4 cv = *(const f32x4*)(Bp + j * 16);   // broadcast across cl
#pragma unroll
      for (int rb = 0; rb < 2; ++rb) {
        f32x4 sa = cv;
        sa = __builtin_amdgcn_mfma_f32_16x16x32_bf16(kf0, qf[rb][0], sa, 0, 0, 0);
        sa = __builtin_amdgcn_mfma_f32_16x16x32_bf16(kf1, qf[rb][1], sa, 0, 0, 0);
        s[rb][j] = sa;
      }
    }
    __builtin_amdgcn_s_setprio(0);

    // p = exp2(s + bias) in registers (masked -> exact 0); l accumulates f32x4
#pragma unroll
    for (int rb = 0; rb < 2; ++rb)
#pragma unroll
      for (int j = 0; j < 4; ++j) {
#pragma unroll
        for (int r = 0; r < 4; ++r)
          s[rb][j][r] = __builtin_amdgcn_exp2f(s[rb][j][r]);
        lacc[rb] += s[rb][j];
      }

    // pack P to bf16 lane-locally: pf[c] = keys {32c+4g+r} ++ {32c+16+4g+r}
    bf16x8 pf[2][2];
#pragma unroll
    for (int rb = 0; rb < 2; ++rb)
#pragma unroll
      for (int c = 0; c < 2; ++c) {
        bf16x8 v;
        v[0] = (__bf16)s[rb][2 * c][0];
        v[1] = (__bf16)s[rb][2 * c][1];
        v[2] = (__bf16)s[rb][2 * c][2];
        v[3] = (__bf16)s[rb][2 * c][3];
        v[4] = (__bf16)s[rb][2 * c + 1][0];
        v[5] = (__bf16)s[rb][2 * c + 1][1];
        v[6] = (__bf16)s[rb][2 * c + 1][2];
        v[7] = (__bf16)s[rb][2 * c + 1][3];
        pf[rb][c] = v;
      }

    // O^T += V^T P^T. Permuted-V storage: lane (cl,q) frag c's 8 k-slot
    // elements are contiguous at chunk 4c+q -> single b128 (floor pattern).
    __builtin_amdgcn_s_setprio(1);
#pragma unroll
    for (int dj = 0; dj < 4; ++dj) {
      const short* vrow = Vp + (dj * 16 + cl) * 64;
#pragma unroll
      for (int c = 0; c < 2; ++c) {
        bf16x8 vfc = lds_frag(vrow + (((4 * c + q) ^ sw) * 8));
#pragma unroll
        for (int rb = 0; rb < 2; ++rb)
          oacc[rb][dj] = __builtin_amdgcn_mfma_f32_16x16x32_bf16(vfc, pf[rb][c], oacc[rb][dj], 0, 0, 0);
      }
    }
    __builtin_amdgcn_s_setprio(0);
  };

  // main loop: 8 iters x 2 ping-pong phases = 16 tiles of 128 keys.
  // Each phase: ONE barrier, then DMA-stage the next tile into the other
  // buffer (lands during this phase's compute), then compute.
  for (int it = 0; it < 8; ++it) {
    int s0 = it * 128;                 // half-space key offset
    __syncthreads();                   // drains bufA loads (issued last phase)
    stage(bufB, s0 + 64);              // overwrites Q region on it=0 (qf in regs)
    compute(bufA, s0);
    __syncthreads();                   // drains bufB loads
    if (it < 7) stage(bufA, s0 + 128);
    compute(bufB, s0 + 64);
  }

  // ---- combine kv-halves through LDS (O,l are linear in the key axis) ----
  __syncthreads();                       // all compute reads of LDS done
  float hl[2];
#pragma unroll
  for (int rb = 0; rb < 2; ++rb)
    hl[rb] = lacc[rb][0] + lacc[rb][1] + lacc[rb][2] + lacc[rb][3];

  float* redO = (float*)smem;            // 32 KB (bufA region)
  float* redL = (float*)(smem + 16384);  // 2 KB (bufB region)
  const int slot = wg * 64 + lane;
  if (kvh) {
#pragma unroll
    for (int rb = 0; rb < 2; ++rb) {
#pragma unroll
      for (int dj = 0; dj < 4; ++dj) {
        int qi = (rb * 4 + dj) ^ (lane & 7);   // XOR-swizzle: spread banks
        *(f32x4*)(redO + slot * 32 + qi * 4) = oacc[rb][dj];
      }
      redL[slot * 2 + rb] = hl[rb];
    }
  }
  __syncthreads();
  if (kvh) return;
#pragma unroll
  for (int rb = 0; rb < 2; ++rb) {
    hl[rb] += redL[slot * 2 + rb];
#pragma unroll
    for (int dj = 0; dj < 4; ++dj) {
      int qi = (rb * 4 + dj) ^ (lane & 7);
      oacc[rb][dj] += *(const f32x4*)(redO + slot * 32 + qi * 4);
    }
  }
  // l: sum over the 4 g-lane groups (lanes ^16, ^32 share the same cl)
#pragma unroll
  for (int rb = 0; rb < 2; ++rb) {
    hl[rb] += __shfl_xor(hl[rb], 16);
    hl[rb] += __shfl_xor(hl[rb], 32);
  }

  // finalize: O^T layout -> lane (cl,g) reg r holds O[q=wg*32+rb*16+cl]
  // [d = dj*16 + 4g + r]; 4 consecutive d per reg -> short4 stores.
#pragma unroll
  for (int rb = 0; rb < 2; ++rb) {
    float inv = (hl[rb] > 0.0f) ? 1.0f / hl[rb] : 0.0f;
    size_t row = rowQ0 + wg * 32 + rb * 16 + cl;
#pragma unroll
    for (int dj = 0; dj < 4; ++dj) {
      short4 o4;
      o4.x = f2bf(oacc[rb][dj][0] * inv);
      o4.y = f2bf(oacc[rb][dj][1] * inv);
      o4.z = f2bf(oacc[rb][dj][2] * inv);
      o4.w = f2bf(oacc[rb][dj][3] * inv);
      *(short4*)(ctx + row * D_MODEL + h * DHEAD + dj * 16 + q * 4) = o4;
    }
  }
}

// ---------------------------------------------------------------------------
extern "C" void kernel_launch(void* const* d_in, const int* in_sizes, int n_in,
                              void* d_out, int out_size, void* d_ws, size_t ws_size,
                              hipStream_t stream) {
  (void)in_sizes; (void)n_in; (void)out_size; (void)ws_size;

  const float* x  = (const float*)d_in[0];
  const int*   pm = (const int*)  d_in[1];
  const float* Wq = (const float*)d_in[2];
  const float* bq = (const float*)d_in[3];
  const float* Wk = (const float*)d_in[4];
  const float* bk = (const float*)d_in[5];
  const float* Wv = (const float*)d_in[6];
  const float* bv = (const float*)d_in[7];
  const float* Wo = (const float*)d_in[8];
  const float* bo = (const float*)d_in[9];

  const size_t WMAT = (size_t)D_MODEL * D_MODEL;   // 1M elems
  const size_t TOKD = (size_t)M_TOK * D_MODEL;     // 4M elems

  short* base = (short*)d_ws;
  short* Wt = base;              // 4 transposed bf16 weights: 8 MB
  short* xb = base + 4 * WMAT;   // bf16 x: 8 MB
  short* Qw = xb + TOKD;         // 8 MB (z=0, pre-scaled by QSCALE)
  short* Kw = Qw + TOKD;         // 8 MB (z=1)
  short* Vtw = Kw + TOKD;        // 8 MB Vt[b][n][s], masked rows zeroed, key-permuted
  short* Cw = Vtw + TOKD;        // 8 MB  (total 48 MB of ws)

  prep<<<dim3(16, 16, 5), 256, 0, stream>>>(x, xb, Wq, Wk, Wv, Wo, Wt);
  gemm128<false, true, 128><<<dim3(M_TOK / 128, D_MODEL / 128, 3), 256, 0, stream>>>(
      xb, Wt, bq, bk, bv, Qw, Vtw, pm);
  attn_flash<<<dim3(SEQ / 128, NHEAD, BATCH), 512, 0, stream>>>(Qw, Kw, Vtw, pm, Cw);
  gemm128<true, false, 64><<<dim3(M_TOK / 128, D_MODEL / 64, 1), 256, 0, stream>>>(
      Cw, Wt + 3 * WMAT, bo, bo, bo, d_out, nullptr, nullptr);
}

// Round 9
// 193.677 us; speedup vs baseline: 1.0299x; 1.0122x over previous
//
#include <hip/hip_runtime.h>
#include <hip/hip_bf16.h>
#include <stdint.h>
#include <math.h>

// Problem constants
#define D_MODEL 1024
#define NHEAD   16
#define DHEAD   64
#define BATCH   2
#define SEQ     2048
#define M_TOK   (BATCH * SEQ)   // 4096 tokens

// Q pre-scale: 1/sqrt(DHEAD) * log2(e), folded into the Q projection so the
// QK^T MFMA result is directly the exp2 argument.
#define QSCALE 0.18033688011112042f

typedef __attribute__((ext_vector_type(8))) short   short8;
typedef __attribute__((ext_vector_type(8))) __bf16  bf16x8;
typedef __attribute__((ext_vector_type(4))) float   f32x4;

__device__ inline short f2bf(float f) {           // RNE
  unsigned int u = __builtin_bit_cast(unsigned int, f);
  unsigned int r = (u + 0x7FFFu + ((u >> 16) & 1u)) >> 16;
  return (short)(unsigned short)r;
}
__device__ inline short f2bf_fast(float f) {      // round-nearest (ties away), 2 ops
  unsigned int u = __builtin_bit_cast(unsigned int, f);
  return (short)(unsigned short)((u + 0x8000u) >> 16);
}

// async global -> LDS, 16B per lane. LDS dest must be wave-uniform base + lane*16.
__device__ inline void gl_lds16(const void* g, void* l) {
  __builtin_amdgcn_global_load_lds((__attribute__((address_space(1))) void*)(g),
                                   (__attribute__((address_space(3))) void*)(l),
                                   16, 0, 0);
}

__device__ inline bf16x8 lds_frag(const short* p) {
  return *(const bf16x8*)(p);
}

// ---------------------------------------------------------------------------
// Prep kernel (fused): z=0..3 -> transpose+convert weight matrix z
// (W[k][n] fp32 -> Wt[n][k] bf16); z=4 -> convert x fp32 -> bf16.
// Grid (16,16,5), 256 threads. One launch instead of two.
// ---------------------------------------------------------------------------
__global__ __launch_bounds__(256) void prep(const float* __restrict__ x,
                                            short* __restrict__ xb,
                                            const float* __restrict__ w0,
                                            const float* __restrict__ w1,
                                            const float* __restrict__ w2,
                                            const float* __restrict__ w3,
                                            short* __restrict__ out) {
  const int t = threadIdx.x;
  if (blockIdx.z == 4) {
    // convert x: 256 blocks (by*16+bx), 16384 elems each
    size_t base = ((size_t)blockIdx.y * 16 + blockIdx.x) * 16384;
    const float* in = x + base;
    short* o = xb + base;
#pragma unroll
    for (int i = 0; i < 16; ++i) {
      f32x4 v = *(const f32x4*)(in + (size_t)t * 4 + i * 1024);
      short4 s4;
      s4.x = f2bf(v[0]); s4.y = f2bf(v[1]); s4.z = f2bf(v[2]); s4.w = f2bf(v[3]);
      *(short4*)(o + (size_t)t * 4 + i * 1024) = s4;
    }
    return;
  }
  __shared__ short tile[64][72];
  const float* W = blockIdx.z == 0 ? w0 : blockIdx.z == 1 ? w1 : blockIdx.z == 2 ? w2 : w3;
  short* O = out + (size_t)blockIdx.z * (D_MODEL * (size_t)D_MODEL);
  int n0 = blockIdx.x * 64, k0 = blockIdx.y * 64;
#pragma unroll
  for (int i = 0; i < 16; ++i) {
    int idx = t + 256 * i;
    int r = idx >> 6, c = idx & 63;
    tile[r][c] = f2bf(W[(size_t)(k0 + r) * D_MODEL + n0 + c]);
  }
  __syncthreads();
#pragma unroll
  for (int i = 0; i < 16; ++i) {
    int idx = t + 256 * i;
    int r = idx >> 6, c = idx & 63;
    O[(size_t)(n0 + r) * D_MODEL + k0 + c] = tile[c][r];
  }
}

// ---------------------------------------------------------------------------
// GEMM v3: out[m][n] = A[m][k] * Bt[n][k]^T + bias[n]  (bf16 in, fp32 acc)
// 128xTN tile, 256 threads (4 waves, 64x(TN/2) per wave), BK=32 packed rows.
// R8 diagnosis of v2 (~47us): per-step time 3530cy vs ~400cy of wave work --
// __syncthreads' vmcnt(0) drain waits on the prefetch issued ~300cy earlier
// (HBM ~900cy) => per-step latency stall, not LDS saturation (util ~43%).
// v3 = T4 counted-vmcnt (m218: counted-vs-drain0 +38-73%): 3-buffer rotation
// (mod 3) + raw s_barrier + s_waitcnt vmcnt(NLD) that retires only the
// PREVIOUS stage's loads, leaving the just-issued prefetch in flight with a
// full step of slack. Race audit: buf[(ks+1)%3]'s writes are 2 barriers after
// its last reader compute(ks-2); frag ds_reads retire pre-barrier via
// compiler lgkmcnt before MFMA use (m201's proven pattern).
// LDS: QKV 48KB, proj 36KB -> still 3 blocks/CU.
// QKV launch (VT=true): z=0 -> Q scaled by QSCALE; z=2 -> V written transposed
// with MASKED KEY ROWS ZEROED (pm[b][s]==1 -> 0) and the key axis PERMUTED
// within each 32-key block so the attention PV step reads single b128
// fragments (R3: unpermuted cost 4.27M conflict cycles; R4: 74K).
// ---------------------------------------------------------------------------
template <bool OUTF32, bool VT, int TN>
__global__ __launch_bounds__(256) void gemm128(const short* __restrict__ A,
                                               const short* __restrict__ Bt_base,
                                               const float* __restrict__ b0,
                                               const float* __restrict__ b1,
                                               const float* __restrict__ b2,
                                               void* __restrict__ out_base,
                                               short* __restrict__ vt,
                                               const int* __restrict__ pm) {
  constexpr int NI  = TN / 32;        // per-wave n-subtiles (4 or 2)
  constexpr int NBI = (TN * 4) / 256; // B stage slots per thread (2 or 1)
  constexpr int NLD = 2 + NBI;        // gl_lds issued per thread per stage
  const int z = blockIdx.z;
  const short* Bt   = Bt_base + (size_t)z * (D_MODEL * (size_t)D_MODEL);
  const float* bias = (z == 0) ? b0 : (z == 1) ? b1 : b2;

  // per-buffer A: [64 row-pairs][8 slots x 8 shorts] = 8KB; B: TN/2 pairs.
  __shared__ short As[3][128 * 32];   // 24 KB total
  __shared__ short Bs[3][TN * 32];    // 24 or 12 KB total

  const int t = threadIdx.x;
  const int lane = t & 63;
  const int wid = t >> 6;
  const int wm = (wid >> 1) * 64, wn = (wid & 1) * (TN / 2);
  const int m0 = blockIdx.x * 128, n0 = blockIdx.y * TN;
  const int cl = lane & 15, q = lane >> 4;

  f32x4 acc[4][NI];
#pragma unroll
  for (int i = 0; i < 4; ++i)
#pragma unroll
    for (int j = 0; j < NI; ++j) acc[i][j] = 0.0f;

  // stage K-step ks (32 cols) into buffer ks%3. Slot d holds global
  // (row = 2*(d>>3) + (x>>2), col = (x&3)*8) with x = (d&7)^((d>>3)&7):
  // dest linear in d (gl_lds requirement), swizzle carried by the source.
  auto stage = [&](int ks) {
    const int bi = ks % 3;
    const int k0 = ks * 32;
#pragma unroll
    for (int i = 0; i < 2; ++i) {       // A: 512 slots
      int d = t + 256 * i;
      int rp = d >> 3, x = (d & 7) ^ (rp & 7);
      gl_lds16(A + (size_t)(m0 + rp * 2 + (x >> 2)) * D_MODEL + k0 + (x & 3) * 8,
               (void*)(As[bi] + d * 8));
    }
#pragma unroll
    for (int i = 0; i < NBI; ++i) {     // B: TN*4 slots
      int d = t + 256 * i;
      int rp = d >> 3, x = (d & 7) ^ (rp & 7);
      gl_lds16(Bt + (size_t)(n0 + rp * 2 + (x >> 2)) * D_MODEL + k0 + (x & 3) * 8,
               (void*)(Bs[bi] + d * 8));
    }
  };

  stage(0);
  for (int ks = 0; ks < 32; ++ks) {
    if (ks + 1 < 32) {
      stage(ks + 1);                 // prefetch stays IN FLIGHT across barrier
      if constexpr (NLD == 4)
        asm volatile("s_waitcnt vmcnt(4)" ::: "memory");   // retire stage(ks) only
      else
        asm volatile("s_waitcnt vmcnt(3)" ::: "memory");
    } else {
      asm volatile("s_waitcnt vmcnt(0)" ::: "memory");     // tail: drain all
    }
    __builtin_amdgcn_s_barrier();

    const short* Ap = As[ks % 3];
    const short* Bp = Bs[ks % 3];

    bf16x8 af[4], bfr[NI];
#pragma unroll
    for (int mi = 0; mi < 4; ++mi) {
      int row = wm + mi * 16 + cl;
      int rp = row >> 1;
      int pos = (((row & 1) << 2) | q) ^ (rp & 7);
      af[mi] = lds_frag(Ap + rp * 64 + pos * 8);
    }
#pragma unroll
    for (int ni = 0; ni < NI; ++ni) {
      int row = wn + ni * 16 + cl;
      int rp = row >> 1;
      int pos = (((row & 1) << 2) | q) ^ (rp & 7);
      bfr[ni] = lds_frag(Bp + rp * 64 + pos * 8);
    }
#pragma unroll
    for (int mi = 0; mi < 4; ++mi)
#pragma unroll
      for (int ni = 0; ni < NI; ++ni)
        acc[mi][ni] = __builtin_amdgcn_mfma_f32_16x16x32_bf16(af[mi], bfr[ni], acc[mi][ni], 0, 0, 0);
  }

  // Epilogue: C/D layout col=lane&15, row=(lane>>4)*4+reg
  const float oscale = (VT && z == 0) ? QSCALE : 1.0f;
  int4 mm[4];
  if (VT && z == 2) {
#pragma unroll
    for (int mi = 0; mi < 4; ++mi) {
      int rbase = m0 + wm + mi * 16 + q * 4;
      mm[mi] = *(const int4*)(pm + (size_t)(rbase >> 11) * SEQ + (rbase & (SEQ - 1)));
    }
  }
#pragma unroll
  for (int ni = 0; ni < NI; ++ni) {
    int col = n0 + wn + ni * 16 + cl;
    float bv = bias[col];
#pragma unroll
    for (int mi = 0; mi < 4; ++mi) {
      int rbase = m0 + wm + mi * 16 + q * 4;
      if (VT && z == 2) {
        short4 o4;
        o4.x = (mm[mi].x == 1) ? (short)0 : f2bf_fast(acc[mi][ni][0] + bv);
        o4.y = (mm[mi].y == 1) ? (short)0 : f2bf_fast(acc[mi][ni][1] + bv);
        o4.z = (mm[mi].z == 1) ? (short)0 : f2bf_fast(acc[mi][ni][2] + bv);
        o4.w = (mm[mi].w == 1) ? (short)0 : f2bf_fast(acc[mi][ni][3] + bv);
        int btok = rbase >> 11;           // token block -> batch
        int s    = rbase & (SEQ - 1);
        // key-axis permutation within each 32-key block: storage p holds key
        // with bits rearranged (p[4:3]=key[3:2], p[2]=key[4], p[1:0]=key[1:0])
        // -> attn PV reads become contiguous b128 fragments. s is 4-aligned so
        // the short4 store stays contiguous.
        int sp = (s & ~31) | ((s & 16) >> 2) | ((s & 12) << 1) | (s & 3);
        *(short4*)(vt + (size_t)btok * ((size_t)D_MODEL * SEQ) + (size_t)col * SEQ + sp) = o4;
      } else {
#pragma unroll
        for (int r = 0; r < 4; ++r) {
          float v = (acc[mi][ni][r] + bv) * oscale;
          size_t idx = (size_t)(rbase + r) * D_MODEL + col;
          if (OUTF32) {
            ((float*)out_base)[idx] = v;
          } else {
            short* out = (short*)out_base + (size_t)z * ((size_t)M_TOK * D_MODEL);
            out[idx] = f2bf_fast(v);
          }
        }
      }
    }
  }
}

// ---------------------------------------------------------------------------
// Flash attention v11 = v9 (proven 48.0us) + T5 s_setprio around MFMA
// clusters (R8: 47.8us, setprio ~neutral, kept). R8 replay data: same 47.9us
// at FETCH 8.4MB (L2-warm) as 69.8MB -> attn is NOT HBM-bound; it sits at
// the latency/LDS structural plateau. Its per-phase compute (~7Kcy) already
// covers the prefetch latency, so the barrier drain is free -- counted-vmcnt
// would gain nothing here. Unchanged this round.
// ---------------------------------------------------------------------------
__global__ __launch_bounds__(512) void attn_flash(const short* __restrict__ Q,
                                                  const short* __restrict__ K,
                                                  const short* __restrict__ Vt,
                                                  const int*   __restrict__ mask,
                                                  short* __restrict__ ctx) {
  const int qb = blockIdx.x;   // 0..15
  const int h  = blockIdx.y;   // 0..15
  const int b  = blockIdx.z;   // 0..1

  // shorts: bufA[16384] | bufB[16384] | Usf f32[2048] (additive bias)
  // bufX = K[2 halves][64key][64d] ++ Vt[2 halves][64d][64key], swizzled.
  // prologue: Q tile staged into bufB[0:8192]. epilogue: redO over bufA,
  // redL over bufB start.
  __shared__ __align__(16) short smem[36864];
  short* bufA = smem;
  short* bufB = smem + 16384;
  float* Usf  = (float*)(smem + 32768);

  const int t = threadIdx.x;
  const int lane = t & 63;
  const int wid = t >> 6;           // 0..7
  const int wg  = wid >> 1;         // row-group 0..3 (32 q-rows each)
  const int kvh = wid & 1;          // kv half: keys [kvh*1024, kvh*1024+1024)
  const int cl = lane & 15, q = lane >> 4;
  const int sw = cl & 7;

  const size_t rowQ0 = (size_t)b * SEQ + (size_t)qb * 128;
  const size_t rowK0 = (size_t)b * SEQ;
  const size_t vbase = ((size_t)b * D_MODEL + h * DHEAD) * SEQ;

  // per-thread staging addresses (thread t owns LDS chunk t*16B; global
  // source pre-swizzled so LDS reads can XOR-deswizzle)
  const int srow = t >> 3, scp = t & 7;
  const int scol = (scp ^ (srow & 7)) * 8;
  const short* Kg0 = K + (rowK0 + srow) * D_MODEL + h * DHEAD + scol;
  const short* Kg1 = K + (rowK0 + 1024 + srow) * D_MODEL + h * DHEAD + scol;
  const short* Vg0 = Vt + vbase + (size_t)srow * SEQ + scol;
  const short* Vg1 = Vt + vbase + (size_t)srow * SEQ + 1024 + scol;

  // DMA-stage one 128-key tile (64/half K + V) into buf. 4 chunks/thread.
  auto stage = [&](short* buf, int sn) {
    gl_lds16(Kg0 + (size_t)sn * D_MODEL, (void*)(buf + t * 8));
    gl_lds16(Kg1 + (size_t)sn * D_MODEL, (void*)(buf + 4096 + t * 8));
    gl_lds16(Vg0 + sn,                   (void*)(buf + 8192 + t * 8));
    gl_lds16(Vg1 + sn,                   (void*)(buf + 8192 + 4096 + t * 8));
  };

  // prologue: KV tile 0 -> bufA; Q tile -> bufB[0:8192]; mask bias -> Usf
  stage(bufA, 0);
#pragma unroll
  for (int i = 0; i < 2; ++i) {
    int c = t + 512 * i;
    int row = c >> 3, cp = c & 7;
    gl_lds16(Q + (rowQ0 + row) * D_MODEL + h * DHEAD + ((cp ^ (row & 7)) * 8),
             (void*)(bufB + c * 8));
  }
  {
    int4 mv = *(const int4*)(mask + (size_t)b * SEQ + t * 4);
    f32x4 u4;
    u4[0] = (mv.x == 1) ? -1e30f : 0.0f;
    u4[1] = (mv.y == 1) ? -1e30f : 0.0f;
    u4[2] = (mv.z == 1) ? -1e30f : 0.0f;
    u4[3] = (mv.w == 1) ? -1e30f : 0.0f;
    *(f32x4*)(Usf + t * 4) = u4;
  }
  __syncthreads();

  // Register-resident Q fragments: wave owns rows [32*wg, 32*wg+32)
  bf16x8 qf[2][2];
#pragma unroll
  for (int rb = 0; rb < 2; ++rb) {
    int row = wg * 32 + rb * 16 + cl;
    qf[rb][0] = lds_frag(bufB + row * 64 + (q ^ sw) * 8);
    qf[rb][1] = lds_frag(bufB + row * 64 + ((4 + q) ^ sw) * 8);
  }

  f32x4 lacc[2], oacc[2][4];
#pragma unroll
  for (int rb = 0; rb < 2; ++rb) {
    lacc[rb] = 0.0f;
#pragma unroll
    for (int dj = 0; dj < 4; ++dj) oacc[rb][dj] = 0.0f;
  }

  // one 128-key tile (64 keys from this wave's half)
  auto compute = [&](const short* buf, int s0) {
    const short* Kp = buf + kvh * 4096;
    const short* Vp = buf + 8192 + kvh * 4096;
    const float* Bp = Usf + kvh * 1024 + s0 + 4 * q;

    // S^T = K Q^T + bias (C-init): C row = key 4g+r (tile j), col = q-row cl
    f32x4 s[2][4];
    __builtin_amdgcn_s_setprio(1);
#pragma unroll
    for (int j = 0; j < 4; ++j) {
      bf16x8 kf0 = lds_frag(Kp + (j * 16 + cl) * 64 + (q ^ sw) * 8);
      bf16x8 kf1 = lds_frag(Kp + (j * 16 + cl) * 64 + ((4 + q) ^ sw) * 8);
      f32x4 cv = *(const f32x4*)(Bp + j * 16);   // broadcast across cl
#pragma unroll
      for (int rb = 0; rb < 2; ++rb) {
        f32x4 sa = cv;
        sa = __builtin_amdgcn_mfma_f32_16x16x32_bf16(kf0, qf[rb][0], sa, 0, 0, 0);
        sa = __builtin_amdgcn_mfma_f32_16x16x32_bf16(kf1, qf[rb][1], sa, 0, 0, 0);
        s[rb][j] = sa;
      }
    }
    __builtin_amdgcn_s_setprio(0);

    // p = exp2(s + bias) in registers (masked -> exact 0); l accumulates f32x4
#pragma unroll
    for (int rb = 0; rb < 2; ++rb)
#pragma unroll
      for (int j = 0; j < 4; ++j) {
#pragma unroll
        for (int r = 0; r < 4; ++r)
          s[rb][j][r] = __builtin_amdgcn_exp2f(s[rb][j][r]);
        lacc[rb] += s[rb][j];
      }

    // pack P to bf16 lane-locally: pf[c] = keys {32c+4g+r} ++ {32c+16+4g+r}
    bf16x8 pf[2][2];
#pragma unroll
    for (int rb = 0; rb < 2; ++rb)
#pragma unroll
      for (int c = 0; c < 2; ++c) {
        bf16x8 v;
        v[0] = (__bf16)s[rb][2 * c][0];
        v[1] = (__bf16)s[rb][2 * c][1];
        v[2] = (__bf16)s[rb][2 * c][2];
        v[3] = (__bf16)s[rb][2 * c][3];
        v[4] = (__bf16)s[rb][2 * c + 1][0];
        v[5] = (__bf16)s[rb][2 * c + 1][1];
        v[6] = (__bf16)s[rb][2 * c + 1][2];
        v[7] = (__bf16)s[rb][2 * c + 1][3];
        pf[rb][c] = v;
      }

    // O^T += V^T P^T. Permuted-V storage: lane (cl,q) frag c's 8 k-slot
    // elements are contiguous at chunk 4c+q -> single b128 (floor pattern).
    __builtin_amdgcn_s_setprio(1);
#pragma unroll
    for (int dj = 0; dj < 4; ++dj) {
      const short* vrow = Vp + (dj * 16 + cl) * 64;
#pragma unroll
      for (int c = 0; c < 2; ++c) {
        bf16x8 vfc = lds_frag(vrow + (((4 * c + q) ^ sw) * 8));
#pragma unroll
        for (int rb = 0; rb < 2; ++rb)
          oacc[rb][dj] = __builtin_amdgcn_mfma_f32_16x16x32_bf16(vfc, pf[rb][c], oacc[rb][dj], 0, 0, 0);
      }
    }
    __builtin_amdgcn_s_setprio(0);
  };

  // main loop: 8 iters x 2 ping-pong phases = 16 tiles of 128 keys.
  // Each phase: ONE barrier, then DMA-stage the next tile into the other
  // buffer (lands during this phase's compute), then compute.
  for (int it = 0; it < 8; ++it) {
    int s0 = it * 128;                 // half-space key offset
    __syncthreads();                   // drains bufA loads (issued last phase)
    stage(bufB, s0 + 64);              // overwrites Q region on it=0 (qf in regs)
    compute(bufA, s0);
    __syncthreads();                   // drains bufB loads
    if (it < 7) stage(bufA, s0 + 128);
    compute(bufB, s0 + 64);
  }

  // ---- combine kv-halves through LDS (O,l are linear in the key axis) ----
  __syncthreads();                       // all compute reads of LDS done
  float hl[2];
#pragma unroll
  for (int rb = 0; rb < 2; ++rb)
    hl[rb] = lacc[rb][0] + lacc[rb][1] + lacc[rb][2] + lacc[rb][3];

  float* redO = (float*)smem;            // 32 KB (bufA region)
  float* redL = (float*)(smem + 16384);  // 2 KB (bufB region)
  const int slot = wg * 64 + lane;
  if (kvh) {
#pragma unroll
    for (int rb = 0; rb < 2; ++rb) {
#pragma unroll
      for (int dj = 0; dj < 4; ++dj) {
        int qi = (rb * 4 + dj) ^ (lane & 7);   // XOR-swizzle: spread banks
        *(f32x4*)(redO + slot * 32 + qi * 4) = oacc[rb][dj];
      }
      redL[slot * 2 + rb] = hl[rb];
    }
  }
  __syncthreads();
  if (kvh) return;
#pragma unroll
  for (int rb = 0; rb < 2; ++rb) {
    hl[rb] += redL[slot * 2 + rb];
#pragma unroll
    for (int dj = 0; dj < 4; ++dj) {
      int qi = (rb * 4 + dj) ^ (lane & 7);
      oacc[rb][dj] += *(const f32x4*)(redO + slot * 32 + qi * 4);
    }
  }
  // l: sum over the 4 g-lane groups (lanes ^16, ^32 share the same cl)
#pragma unroll
  for (int rb = 0; rb < 2; ++rb) {
    hl[rb] += __shfl_xor(hl[rb], 16);
    hl[rb] += __shfl_xor(hl[rb], 32);
  }

  // finalize: O^T layout -> lane (cl,g) reg r holds O[q=wg*32+rb*16+cl]
  // [d = dj*16 + 4g + r]; 4 consecutive d per reg -> short4 stores.
#pragma unroll
  for (int rb = 0; rb < 2; ++rb) {
    float inv = (hl[rb] > 0.0f) ? 1.0f / hl[rb] : 0.0f;
    size_t row = rowQ0 + wg * 32 + rb * 16 + cl;
#pragma unroll
    for (int dj = 0; dj < 4; ++dj) {
      short4 o4;
      o4.x = f2bf(oacc[rb][dj][0] * inv);
      o4.y = f2bf(oacc[rb][dj][1] * inv);
      o4.z = f2bf(oacc[rb][dj][2] * inv);
      o4.w = f2bf(oacc[rb][dj][3] * inv);
      *(short4*)(ctx + row * D_MODEL + h * DHEAD + dj * 16 + q * 4) = o4;
    }
  }
}

// ---------------------------------------------------------------------------
extern "C" void kernel_launch(void* const* d_in, const int* in_sizes, int n_in,
                              void* d_out, int out_size, void* d_ws, size_t ws_size,
                              hipStream_t stream) {
  (void)in_sizes; (void)n_in; (void)out_size; (void)ws_size;

  const float* x  = (const float*)d_in[0];
  const int*   pm = (const int*)  d_in[1];
  const float* Wq = (const float*)d_in[2];
  const float* bq = (const float*)d_in[3];
  const float* Wk = (const float*)d_in[4];
  const float* bk = (const float*)d_in[5];
  const float* Wv = (const float*)d_in[6];
  const float* bv = (const float*)d_in[7];
  const float* Wo = (const float*)d_in[8];
  const float* bo = (const float*)d_in[9];

  const size_t WMAT = (size_t)D_MODEL * D_MODEL;   // 1M elems
  const size_t TOKD = (size_t)M_TOK * D_MODEL;     // 4M elems

  short* base = (short*)d_ws;
  short* Wt = base;              // 4 transposed bf16 weights: 8 MB
  short* xb = base + 4 * WMAT;   // bf16 x: 8 MB
  short* Qw = xb + TOKD;         // 8 MB (z=0, pre-scaled by QSCALE)
  short* Kw = Qw + TOKD;         // 8 MB (z=1)
  short* Vtw = Kw + TOKD;        // 8 MB Vt[b][n][s], masked rows zeroed, key-permuted
  short* Cw = Vtw + TOKD;        // 8 MB  (total 48 MB of ws)

  prep<<<dim3(16, 16, 5), 256, 0, stream>>>(x, xb, Wq, Wk, Wv, Wo, Wt);
  gemm128<false, true, 128><<<dim3(M_TOK / 128, D_MODEL / 128, 3), 256, 0, stream>>>(
      xb, Wt, bq, bk, bv, Qw, Vtw, pm);
  attn_flash<<<dim3(SEQ / 128, NHEAD, BATCH), 512, 0, stream>>>(Qw, Kw, Vtw, pm, Cw);
  gemm128<true, false, 64><<<dim3(M_TOK / 128, D_MODEL / 64, 1), 256, 0, stream>>>(
      Cw, Wt + 3 * WMAT, bo, bo, bo, d_out, nullptr, nullptr);
}

// Round 12
// 192.517 us; speedup vs baseline: 1.0361x; 1.0060x over previous
//
#include <hip/hip_runtime.h>
#include <hip/hip_bf16.h>
#include <stdint.h>
#include <math.h>

// Problem constants
#define D_MODEL 1024
#define NHEAD   16
#define DHEAD   64
#define BATCH   2
#define SEQ     2048
#define M_TOK   (BATCH * SEQ)   // 4096 tokens

// Q pre-scale: 1/sqrt(DHEAD) * log2(e), folded into the Q projection so the
// QK^T MFMA result is directly the exp2 argument.
#define QSCALE 0.18033688011112042f

typedef __attribute__((ext_vector_type(8))) short   short8;
typedef __attribute__((ext_vector_type(8))) __bf16  bf16x8;
typedef __attribute__((ext_vector_type(4))) float   f32x4;

__device__ inline short f2bf(float f) {           // RNE
  unsigned int u = __builtin_bit_cast(unsigned int, f);
  unsigned int r = (u + 0x7FFFu + ((u >> 16) & 1u)) >> 16;
  return (short)(unsigned short)r;
}
__device__ inline short f2bf_fast(float f) {      // round-nearest (ties away), 2 ops
  unsigned int u = __builtin_bit_cast(unsigned int, f);
  return (short)(unsigned short)((u + 0x8000u) >> 16);
}

// async global -> LDS, 16B per lane. LDS dest must be wave-uniform base + lane*16.
__device__ inline void gl_lds16(const void* g, void* l) {
  __builtin_amdgcn_global_load_lds((__attribute__((address_space(1))) void*)(g),
                                   (__attribute__((address_space(3))) void*)(l),
                                   16, 0, 0);
}

__device__ inline bf16x8 lds_frag(const short* p) {
  return *(const bf16x8*)(p);
}

// ---------------------------------------------------------------------------
// Prep kernel (fused): z=0..3 -> transpose+convert weight matrix z
// (W[k][n] fp32 -> Wt[n][k] bf16); z=4 -> convert x fp32 -> bf16.
// Grid (16,16,5), 256 threads. One launch instead of two.
// ---------------------------------------------------------------------------
__global__ __launch_bounds__(256) void prep(const float* __restrict__ x,
                                            short* __restrict__ xb,
                                            const float* __restrict__ w0,
                                            const float* __restrict__ w1,
                                            const float* __restrict__ w2,
                                            const float* __restrict__ w3,
                                            short* __restrict__ out) {
  const int t = threadIdx.x;
  if (blockIdx.z == 4) {
    // convert x: 256 blocks (by*16+bx), 16384 elems each
    size_t base = ((size_t)blockIdx.y * 16 + blockIdx.x) * 16384;
    const float* in = x + base;
    short* o = xb + base;
#pragma unroll
    for (int i = 0; i < 16; ++i) {
      f32x4 v = *(const f32x4*)(in + (size_t)t * 4 + i * 1024);
      short4 s4;
      s4.x = f2bf(v[0]); s4.y = f2bf(v[1]); s4.z = f2bf(v[2]); s4.w = f2bf(v[3]);
      *(short4*)(o + (size_t)t * 4 + i * 1024) = s4;
    }
    return;
  }
  __shared__ short tile[64][72];
  const float* W = blockIdx.z == 0 ? w0 : blockIdx.z == 1 ? w1 : blockIdx.z == 2 ? w2 : w3;
  short* O = out + (size_t)blockIdx.z * (D_MODEL * (size_t)D_MODEL);
  int n0 = blockIdx.x * 64, k0 = blockIdx.y * 64;
#pragma unroll
  for (int i = 0; i < 16; ++i) {
    int idx = t + 256 * i;
    int r = idx >> 6, c = idx & 63;
    tile[r][c] = f2bf(W[(size_t)(k0 + r) * D_MODEL + n0 + c]);
  }
  __syncthreads();
#pragma unroll
  for (int i = 0; i < 16; ++i) {
    int idx = t + 256 * i;
    int r = idx >> 6, c = idx & 63;
    O[(size_t)(n0 + r) * D_MODEL + k0 + c] = tile[c][r];
  }
}

// ---------------------------------------------------------------------------
// GEMM v6: out[m][n] = A[m][k] * Bt[n][k]^T + bias[n]  (bf16 in, fp32 acc)
// 128xTN tile, 256 threads (4 waves, 64x(TN/2) per wave), BK=32 packed rows,
// 3-buffer rotation, counted vmcnt (T4), 2-deep prefetch.
// R11 POST-MORTEM: v5 failed POST-TIMING only (0.0105, narrow race; v4's
// pre-barrier stage failed immediately at 0.179). v5's memory-level schedule
// is provably race-free GIVEN program order, but raw s_barrier is NOT a
// compiler memory fence -> two legal motions re-open the races:
//   (a) stage(ks+2) gl_lds hoisted above s_barrier  -> v4's write race;
//   (b) compute(ks) ds_reads hoisted above s_barrier -> stale-read race
//       (own vmcnt retired, other waves' stage portions not yet landed).
// v6 pins the barrier: s_barrier; sched_barrier(0); asm ""::: "memory".
// Memory ops cannot cross an asm memory clobber in either direction, so the
// emitted order is [vmcnt] < [barrier] < [stage(ks+2)] < [compute(ks)].
// Zero added instructions.
// Window proof (unchanged from v5): in window ks (bar(ks)..bar(ks+1)) the
// only writes target buf (ks-1)%3 (readers finished at bar(ks)) and in-flight
// stage(ks+1) targets (ks+1)%3; readers read ks%3 -- all disjoint.
// vmcnt: outstanding at wait = stage(ks)+stage(ks+1) = 2*NLD; vmcnt(NLD)
// retires stage(ks) only (in-order retirement, m135). Tail: ks=31 -> 0.
// QKV launch (VT=true): z=0 -> Q scaled by QSCALE; z=2 -> V written transposed
// with MASKED KEY ROWS ZEROED (pm[b][s]==1 -> 0) and the key axis PERMUTED
// within each 32-key block so the attention PV step reads single b128
// fragments (R3: unpermuted cost 4.27M conflict cycles; R4: 74K).
// ---------------------------------------------------------------------------
template <bool OUTF32, bool VT, int TN>
__global__ __launch_bounds__(256) void gemm128(const short* __restrict__ A,
                                               const short* __restrict__ Bt_base,
                                               const float* __restrict__ b0,
                                               const float* __restrict__ b1,
                                               const float* __restrict__ b2,
                                               void* __restrict__ out_base,
                                               short* __restrict__ vt,
                                               const int* __restrict__ pm) {
  constexpr int NI  = TN / 32;        // per-wave n-subtiles (4 or 2)
  constexpr int NBI = (TN * 4) / 256; // B stage slots per thread (2 or 1)
  constexpr int NLD = 2 + NBI;        // gl_lds issued per thread per stage
  const int z = blockIdx.z;
  const short* Bt   = Bt_base + (size_t)z * (D_MODEL * (size_t)D_MODEL);
  const float* bias = (z == 0) ? b0 : (z == 1) ? b1 : b2;

  // per-buffer A: [64 row-pairs][8 slots x 8 shorts] = 8KB; B: TN/2 pairs.
  __shared__ short As[3][128 * 32];   // 24 KB total
  __shared__ short Bs[3][TN * 32];    // 24 or 12 KB total

  const int t = threadIdx.x;
  const int lane = t & 63;
  const int wid = t >> 6;
  const int wm = (wid >> 1) * 64, wn = (wid & 1) * (TN / 2);
  const int m0 = blockIdx.x * 128, n0 = blockIdx.y * TN;
  const int cl = lane & 15, q = lane >> 4;

  f32x4 acc[4][NI];
#pragma unroll
  for (int i = 0; i < 4; ++i)
#pragma unroll
    for (int j = 0; j < NI; ++j) acc[i][j] = 0.0f;

  // stage K-step ks (32 cols) into buffer ks%3. Slot d holds global
  // (row = 2*(d>>3) + (x>>2), col = (x&3)*8) with x = (d&7)^((d>>3)&7):
  // dest linear in d (gl_lds requirement), swizzle carried by the source.
  auto stage = [&](int ks) {
    const int bi = ks % 3;
    const int k0 = ks * 32;
#pragma unroll
    for (int i = 0; i < 2; ++i) {       // A: 512 slots
      int d = t + 256 * i;
      int rp = d >> 3, x = (d & 7) ^ (rp & 7);
      gl_lds16(A + (size_t)(m0 + rp * 2 + (x >> 2)) * D_MODEL + k0 + (x & 3) * 8,
               (void*)(As[bi] + d * 8));
    }
#pragma unroll
    for (int i = 0; i < NBI; ++i) {     // B: TN*4 slots
      int d = t + 256 * i;
      int rp = d >> 3, x = (d & 7) ^ (rp & 7);
      gl_lds16(Bt + (size_t)(n0 + rp * 2 + (x >> 2)) * D_MODEL + k0 + (x & 3) * 8,
               (void*)(Bs[bi] + d * 8));
    }
  };

  stage(0);
  stage(1);
  for (int ks = 0; ks < 32; ++ks) {
    // retire stage(ks) only; stage(ks+1) stays in flight across the barrier
    if (ks + 1 < 32) {
      if constexpr (NLD == 4)
        asm volatile("s_waitcnt vmcnt(4)" ::: "memory");
      else
        asm volatile("s_waitcnt vmcnt(3)" ::: "memory");
    } else {
      asm volatile("s_waitcnt vmcnt(0)" ::: "memory");     // tail: drain all
    }
    __builtin_amdgcn_s_barrier();
    // Pin the barrier as a code-motion fence (raw s_barrier is not a compiler
    // memory fence): nothing below may hoist above it, in particular
    // stage(ks+2)'s gl_lds writes and compute(ks)'s ds_reads.
    __builtin_amdgcn_sched_barrier(0);
    asm volatile("" ::: "memory");
    // AFTER the pinned barrier: all waves' compute(ks-1) done -> buf (ks-1)%3
    // is reader-free -> staging (ks+2)%3 == (ks-1)%3 is race-free.
    if (ks + 2 < 32) stage(ks + 2);

    const short* Ap = As[ks % 3];
    const short* Bp = Bs[ks % 3];

    bf16x8 af[4], bfr[NI];
#pragma unroll
    for (int mi = 0; mi < 4; ++mi) {
      int row = wm + mi * 16 + cl;
      int rp = row >> 1;
      int pos = (((row & 1) << 2) | q) ^ (rp & 7);
      af[mi] = lds_frag(Ap + rp * 64 + pos * 8);
    }
#pragma unroll
    for (int ni = 0; ni < NI; ++ni) {
      int row = wn + ni * 16 + cl;
      int rp = row >> 1;
      int pos = (((row & 1) << 2) | q) ^ (rp & 7);
      bfr[ni] = lds_frag(Bp + rp * 64 + pos * 8);
    }
#pragma unroll
    for (int mi = 0; mi < 4; ++mi)
#pragma unroll
      for (int ni = 0; ni < NI; ++ni)
        acc[mi][ni] = __builtin_amdgcn_mfma_f32_16x16x32_bf16(af[mi], bfr[ni], acc[mi][ni], 0, 0, 0);
  }

  // Epilogue: C/D layout col=lane&15, row=(lane>>4)*4+reg
  const float oscale = (VT && z == 0) ? QSCALE : 1.0f;
  int4 mm[4];
  if (VT && z == 2) {
#pragma unroll
    for (int mi = 0; mi < 4; ++mi) {
      int rbase = m0 + wm + mi * 16 + q * 4;
      mm[mi] = *(const int4*)(pm + (size_t)(rbase >> 11) * SEQ + (rbase & (SEQ - 1)));
    }
  }
#pragma unroll
  for (int ni = 0; ni < NI; ++ni) {
    int col = n0 + wn + ni * 16 + cl;
    float bv = bias[col];
#pragma unroll
    for (int mi = 0; mi < 4; ++mi) {
      int rbase = m0 + wm + mi * 16 + q * 4;
      if (VT && z == 2) {
        short4 o4;
        o4.x = (mm[mi].x == 1) ? (short)0 : f2bf_fast(acc[mi][ni][0] + bv);
        o4.y = (mm[mi].y == 1) ? (short)0 : f2bf_fast(acc[mi][ni][1] + bv);
        o4.z = (mm[mi].z == 1) ? (short)0 : f2bf_fast(acc[mi][ni][2] + bv);
        o4.w = (mm[mi].w == 1) ? (short)0 : f2bf_fast(acc[mi][ni][3] + bv);
        int btok = rbase >> 11;           // token block -> batch
        int s    = rbase & (SEQ - 1);
        // key-axis permutation within each 32-key block: storage p holds key
        // with bits rearranged (p[4:3]=key[3:2], p[2]=key[4], p[1:0]=key[1:0])
        // -> attn PV reads become contiguous b128 fragments. s is 4-aligned so
        // the short4 store stays contiguous.
        int sp = (s & ~31) | ((s & 16) >> 2) | ((s & 12) << 1) | (s & 3);
        *(short4*)(vt + (size_t)btok * ((size_t)D_MODEL * SEQ) + (size_t)col * SEQ + sp) = o4;
      } else {
#pragma unroll
        for (int r = 0; r < 4; ++r) {
          float v = (acc[mi][ni][r] + bv) * oscale;
          size_t idx = (size_t)(rbase + r) * D_MODEL + col;
          if (OUTF32) {
            ((float*)out_base)[idx] = v;
          } else {
            short* out = (short*)out_base + (size_t)z * ((size_t)M_TOK * D_MODEL);
            out[idx] = f2bf_fast(v);
          }
        }
      }
    }
  }
}

// ---------------------------------------------------------------------------
// Flash attention v11 = v9 (proven 48.0us) + T5 s_setprio around MFMA
// clusters (R8/R9: 47.0-47.8us). R8 replay: same dur at FETCH 8.4MB (L2-warm)
// as 69.8MB -> not HBM-bound; latency/LDS structural plateau. R7 proved the
// traffic-halving restructure (64q/wave) is VGPR-infeasible. Parked.
// (Uses __syncthreads -- full compiler fence -- so no pinning needed here.)
// ---------------------------------------------------------------------------
__global__ __launch_bounds__(512) void attn_flash(const short* __restrict__ Q,
                                                  const short* __restrict__ K,
                                                  const short* __restrict__ Vt,
                                                  const int*   __restrict__ mask,
                                                  short* __restrict__ ctx) {
  const int qb = blockIdx.x;   // 0..15
  const int h  = blockIdx.y;   // 0..15
  const int b  = blockIdx.z;   // 0..1

  // shorts: bufA[16384] | bufB[16384] | Usf f32[2048] (additive bias)
  // bufX = K[2 halves][64key][64d] ++ Vt[2 halves][64d][64key], swizzled.
  // prologue: Q tile staged into bufB[0:8192]. epilogue: redO over bufA,
  // redL over bufB start.
  __shared__ __align__(16) short smem[36864];
  short* bufA = smem;
  short* bufB = smem + 16384;
  float* Usf  = (float*)(smem + 32768);

  const int t = threadIdx.x;
  const int lane = t & 63;
  const int wid = t >> 6;           // 0..7
  const int wg  = wid >> 1;         // row-group 0..3 (32 q-rows each)
  const int kvh = wid & 1;          // kv half: keys [kvh*1024, kvh*1024+1024)
  const int cl = lane & 15, q = lane >> 4;
  const int sw = cl & 7;

  const size_t rowQ0 = (size_t)b * SEQ + (size_t)qb * 128;
  const size_t rowK0 = (size_t)b * SEQ;
  const size_t vbase = ((size_t)b * D_MODEL + h * DHEAD) * SEQ;

  // per-thread staging addresses (thread t owns LDS chunk t*16B; global
  // source pre-swizzled so LDS reads can XOR-deswizzle)
  const int srow = t >> 3, scp = t & 7;
  const int scol = (scp ^ (srow & 7)) * 8;
  const short* Kg0 = K + (rowK0 + srow) * D_MODEL + h * DHEAD + scol;
  const short* Kg1 = K + (rowK0 + 1024 + srow) * D_MODEL + h * DHEAD + scol;
  const short* Vg0 = Vt + vbase + (size_t)srow * SEQ + scol;
  const short* Vg1 = Vt + vbase + (size_t)srow * SEQ + 1024 + scol;

  // DMA-stage one 128-key tile (64/half K + V) into buf. 4 chunks/thread.
  auto stage = [&](short* buf, int sn) {
    gl_lds16(Kg0 + (size_t)sn * D_MODEL, (void*)(buf + t * 8));
    gl_lds16(Kg1 + (size_t)sn * D_MODEL, (void*)(buf + 4096 + t * 8));
    gl_lds16(Vg0 + sn,                   (void*)(buf + 8192 + t * 8));
    gl_lds16(Vg1 + sn,                   (void*)(buf + 8192 + 4096 + t * 8));
  };

  // prologue: KV tile 0 -> bufA; Q tile -> bufB[0:8192]; mask bias -> Usf
  stage(bufA, 0);
#pragma unroll
  for (int i = 0; i < 2; ++i) {
    int c = t + 512 * i;
    int row = c >> 3, cp = c & 7;
    gl_lds16(Q + (rowQ0 + row) * D_MODEL + h * DHEAD + ((cp ^ (row & 7)) * 8),
             (void*)(bufB + c * 8));
  }
  {
    int4 mv = *(const int4*)(mask + (size_t)b * SEQ + t * 4);
    f32x4 u4;
    u4[0] = (mv.x == 1) ? -1e30f : 0.0f;
    u4[1] = (mv.y == 1) ? -1e30f : 0.0f;
    u4[2] = (mv.z == 1) ? -1e30f : 0.0f;
    u4[3] = (mv.w == 1) ? -1e30f : 0.0f;
    *(f32x4*)(Usf + t * 4) = u4;
  }
  __syncthreads();

  // Register-resident Q fragments: wave owns rows [32*wg, 32*wg+32)
  bf16x8 qf[2][2];
#pragma unroll
  for (int rb = 0; rb < 2; ++rb) {
    int row = wg * 32 + rb * 16 + cl;
    qf[rb][0] = lds_frag(bufB + row * 64 + (q ^ sw) * 8);
    qf[rb][1] = lds_frag(bufB + row * 64 + ((4 + q) ^ sw) * 8);
  }

  f32x4 lacc[2], oacc[2][4];
#pragma unroll
  for (int rb = 0; rb < 2; ++rb) {
    lacc[rb] = 0.0f;
#pragma unroll
    for (int dj = 0; dj < 4; ++dj) oacc[rb][dj] = 0.0f;
  }

  // one 128-key tile (64 keys from this wave's half)
  auto compute = [&](const short* buf, int s0) {
    const short* Kp = buf + kvh * 4096;
    const short* Vp = buf + 8192 + kvh * 4096;
    const float* Bp = Usf + kvh * 1024 + s0 + 4 * q;

    // S^T = K Q^T + bias (C-init): C row = key 4g+r (tile j), col = q-row cl
    f32x4 s[2][4];
    __builtin_amdgcn_s_setprio(1);
#pragma unroll
    for (int j = 0; j < 4; ++j) {
      bf16x8 kf0 = lds_frag(Kp + (j * 16 + cl) * 64 + (q ^ sw) * 8);
      bf16x8 kf1 = lds_frag(Kp + (j * 16 + cl) * 64 + ((4 + q) ^ sw) * 8);
      f32x4 cv = *(const f32x4*)(Bp + j * 16);   // broadcast across cl
#pragma unroll
      for (int rb = 0; rb < 2; ++rb) {
        f32x4 sa = cv;
        sa = __builtin_amdgcn_mfma_f32_16x16x32_bf16(kf0, qf[rb][0], sa, 0, 0, 0);
        sa = __builtin_amdgcn_mfma_f32_16x16x32_bf16(kf1, qf[rb][1], sa, 0, 0, 0);
        s[rb][j] = sa;
      }
    }
    __builtin_amdgcn_s_setprio(0);

    // p = exp2(s + bias) in registers (masked -> exact 0); l accumulates f32x4
#pragma unroll
    for (int rb = 0; rb < 2; ++rb)
#pragma unroll
      for (int j = 0; j < 4; ++j) {
#pragma unroll
        for (int r = 0; r < 4; ++r)
          s[rb][j][r] = __builtin_amdgcn_exp2f(s[rb][j][r]);
        lacc[rb] += s[rb][j];
      }

    // pack P to bf16 lane-locally: pf[c] = keys {32c+4g+r} ++ {32c+16+4g+r}
    bf16x8 pf[2][2];
#pragma unroll
    for (int rb = 0; rb < 2; ++rb)
#pragma unroll
      for (int c = 0; c < 2; ++c) {
        bf16x8 v;
        v[0] = (__bf16)s[rb][2 * c][0];
        v[1] = (__bf16)s[rb][2 * c][1];
        v[2] = (__bf16)s[rb][2 * c][2];
        v[3] = (__bf16)s[rb][2 * c][3];
        v[4] = (__bf16)s[rb][2 * c + 1][0];
        v[5] = (__bf16)s[rb][2 * c + 1][1];
        v[6] = (__bf16)s[rb][2 * c + 1][2];
        v[7] = (__bf16)s[rb][2 * c + 1][3];
        pf[rb][c] = v;
      }

    // O^T += V^T P^T. Permuted-V storage: lane (cl,q) frag c's 8 k-slot
    // elements are contiguous at chunk 4c+q -> single b128 (floor pattern).
    __builtin_amdgcn_s_setprio(1);
#pragma unroll
    for (int dj = 0; dj < 4; ++dj) {
      const short* vrow = Vp + (dj * 16 + cl) * 64;
#pragma unroll
      for (int c = 0; c < 2; ++c) {
        bf16x8 vfc = lds_frag(vrow + (((4 * c + q) ^ sw) * 8));
#pragma unroll
        for (int rb = 0; rb < 2; ++rb)
          oacc[rb][dj] = __builtin_amdgcn_mfma_f32_16x16x32_bf16(vfc, pf[rb][c], oacc[rb][dj], 0, 0, 0);
      }
    }
    __builtin_amdgcn_s_setprio(0);
  };

  // main loop: 8 iters x 2 ping-pong phases = 16 tiles of 128 keys.
  // Each phase: ONE barrier, then DMA-stage the next tile into the other
  // buffer (lands during this phase's compute), then compute.
  for (int it = 0; it < 8; ++it) {
    int s0 = it * 128;                 // half-space key offset
    __syncthreads();                   // drains bufA loads (issued last phase)
    stage(bufB, s0 + 64);              // overwrites Q region on it=0 (qf in regs)
    compute(bufA, s0);
    __syncthreads();                   // drains bufB loads
    if (it < 7) stage(bufA, s0 + 128);
    compute(bufB, s0 + 64);
  }

  // ---- combine kv-halves through LDS (O,l are linear in the key axis) ----
  __syncthreads();                       // all compute reads of LDS done
  float hl[2];
#pragma unroll
  for (int rb = 0; rb < 2; ++rb)
    hl[rb] = lacc[rb][0] + lacc[rb][1] + lacc[rb][2] + lacc[rb][3];

  float* redO = (float*)smem;            // 32 KB (bufA region)
  float* redL = (float*)(smem + 16384);  // 2 KB (bufB region)
  const int slot = wg * 64 + lane;
  if (kvh) {
#pragma unroll
    for (int rb = 0; rb < 2; ++rb) {
#pragma unroll
      for (int dj = 0; dj < 4; ++dj) {
        int qi = (rb * 4 + dj) ^ (lane & 7);   // XOR-swizzle: spread banks
        *(f32x4*)(redO + slot * 32 + qi * 4) = oacc[rb][dj];
      }
      redL[slot * 2 + rb] = hl[rb];
    }
  }
  __syncthreads();
  if (kvh) return;
#pragma unroll
  for (int rb = 0; rb < 2; ++rb) {
    hl[rb] += redL[slot * 2 + rb];
#pragma unroll
    for (int dj = 0; dj < 4; ++dj) {
      int qi = (rb * 4 + dj) ^ (lane & 7);
      oacc[rb][dj] += *(const f32x4*)(redO + slot * 32 + qi * 4);
    }
  }
  // l: sum over the 4 g-lane groups (lanes ^16, ^32 share the same cl)
#pragma unroll
  for (int rb = 0; rb < 2; ++rb) {
    hl[rb] += __shfl_xor(hl[rb], 16);
    hl[rb] += __shfl_xor(hl[rb], 32);
  }

  // finalize: O^T layout -> lane (cl,g) reg r holds O[q=wg*32+rb*16+cl]
  // [d = dj*16 + 4g + r]; 4 consecutive d per reg -> short4 stores.
#pragma unroll
  for (int rb = 0; rb < 2; ++rb) {
    float inv = (hl[rb] > 0.0f) ? 1.0f / hl[rb] : 0.0f;
    size_t row = rowQ0 + wg * 32 + rb * 16 + cl;
#pragma unroll
    for (int dj = 0; dj < 4; ++dj) {
      short4 o4;
      o4.x = f2bf(oacc[rb][dj][0] * inv);
      o4.y = f2bf(oacc[rb][dj][1] * inv);
      o4.z = f2bf(oacc[rb][dj][2] * inv);
      o4.w = f2bf(oacc[rb][dj][3] * inv);
      *(short4*)(ctx + row * D_MODEL + h * DHEAD + dj * 16 + q * 4) = o4;
    }
  }
}

// ---------------------------------------------------------------------------
extern "C" void kernel_launch(void* const* d_in, const int* in_sizes, int n_in,
                              void* d_out, int out_size, void* d_ws, size_t ws_size,
                              hipStream_t stream) {
  (void)in_sizes; (void)n_in; (void)out_size; (void)ws_size;

  const float* x  = (const float*)d_in[0];
  const int*   pm = (const int*)  d_in[1];
  const float* Wq = (const float*)d_in[2];
  const float* bq = (const float*)d_in[3];
  const float* Wk = (const float*)d_in[4];
  const float* bk = (const float*)d_in[5];
  const float* Wv = (const float*)d_in[6];
  const float* bv = (const float*)d_in[7];
  const float* Wo = (const float*)d_in[8];
  const float* bo = (const float*)d_in[9];

  const size_t WMAT = (size_t)D_MODEL * D_MODEL;   // 1M elems
  const size_t TOKD = (size_t)M_TOK * D_MODEL;     // 4M elems

  short* base = (short*)d_ws;
  short* Wt = base;              // 4 transposed bf16 weights: 8 MB
  short* xb = base + 4 * WMAT;   // bf16 x: 8 MB
  short* Qw = xb + TOKD;         // 8 MB (z=0, pre-scaled by QSCALE)
  short* Kw = Qw + TOKD;         // 8 MB (z=1)
  short* Vtw = Kw + TOKD;        // 8 MB Vt[b][n][s], masked rows zeroed, key-permuted
  short* Cw = Vtw + TOKD;        // 8 MB  (total 48 MB of ws)

  prep<<<dim3(16, 16, 5), 256, 0, stream>>>(x, xb, Wq, Wk, Wv, Wo, Wt);
  gemm128<false, true, 128><<<dim3(M_TOK / 128, D_MODEL / 128, 3), 256, 0, stream>>>(
      xb, Wt, bq, bk, bv, Qw, Vtw, pm);
  attn_flash<<<dim3(SEQ / 128, NHEAD, BATCH), 512, 0, stream>>>(Qw, Kw, Vtw, pm, Cw);
  gemm128<true, false, 64><<<dim3(M_TOK / 128, D_MODEL / 64, 1), 256, 0, stream>>>(
      Cw, Wt + 3 * WMAT, bo, bo, bo, d_out, nullptr, nullptr);
}